// Round 4
// baseline (687.193 us; speedup 1.0000x reference)
//
#include <hip/hip_runtime.h>
#include <stdint.h>

// Problem constants: B=256, T=128, D=256, H=8, AE=32, DFF=512
#define DEVI static __device__ __forceinline__

typedef __attribute__((ext_vector_type(4))) float f32x4;
typedef __attribute__((ext_vector_type(8))) short bf8;     // 8 bf16 (MFMA A/B frag)
typedef __attribute__((ext_vector_type(4))) unsigned short u16x4;

DEVI unsigned short f2bf(float f) {
  unsigned u = __builtin_bit_cast(unsigned, f);
  u = (u + 0x7FFFu + ((u >> 16) & 1u)) >> 16;
  return (unsigned short)u;
}
DEVI float bf2f(unsigned short s) {
  return __builtin_bit_cast(float, ((unsigned)s) << 16);
}
// packed f32x2 -> bf16x2 (src0 -> low half)
DEVI unsigned cvt_pk_bf16(float lo, float hi) {
  unsigned r;
  asm("v_cvt_pk_bf16_f32 %0, %1, %2" : "=v"(r) : "v"(lo), "v"(hi));
  return r;
}
// LDS XOR swizzle: frag reads 2-way (free); staging writes ~4-8 way.
DEVI int swz(int row) { return (((row >> 2) ^ row) & 7) << 4; }

// ---------------------------------------------------------------------------
// Per-t batched GEMM: C[b,t,n] = sum_k A[b,t,k] * W[t,k,n]
// A bf16 (B,128,Ka) read as direct global MFMA frags (16B contiguous, L2-hot).
// W fp32 staged to bf16 LDS (double-buffered, cvt_pk paired-k, 1 barrier/tile).
// BM=256 (whole batch -> each weight element fetched once), BN=128, BK=64.
// ---------------------------------------------------------------------------
template<bool OUT_BF16>
__global__ __launch_bounds__(256)
void gemm_tk(const unsigned short* __restrict__ A, const float* __restrict__ W,
             void* __restrict__ C, int Ka, int N)
{
  const int t = blockIdx.y;
  const int n0blk = blockIdx.x * 128;
  const int tid = threadIdx.x;
  const int lane = tid & 63;
  const int wv = tid >> 6;
  const int wrow = wv * 64;

  __shared__ short Ws[2][128 * 64];  // [n][k] swizzled (W^T), 2 x 16KB

  f32x4 acc[4][8];
#pragma unroll
  for (int i = 0; i < 4; ++i)
#pragma unroll
    for (int j = 0; j < 8; ++j) acc[i][j] = f32x4{0.f, 0.f, 0.f, 0.f};

  const long ldA = 128L * Ka;
  const unsigned short* Ab = A + (long)t * Ka;
  const float* Wb = W + (long)t * Ka * N + n0blk;

  const int n0 = (tid & 31) * 4;   // 4 consecutive n rows per thread
  const int kp0 = tid >> 5;        // k-pair group 0..7

  f32x4 wlo[4], whi[4];
  // preload W k-tile 0 into regs
#pragma unroll
  for (int it = 0; it < 4; ++it) {
    const long k2 = (long)(kp0 + it * 8) * 2;
    wlo[it] = *reinterpret_cast<const f32x4*>(Wb + k2 * N + n0);
    whi[it] = *reinterpret_cast<const f32x4*>(Wb + (k2 + 1) * N + n0);
  }
  // stage tile 0 -> Ws[0]
#pragma unroll
  for (int it = 0; it < 4; ++it) {
    const int kp = kp0 + it * 8;
#pragma unroll
    for (int j = 0; j < 4; ++j) {
      const int n = n0 + j;
      const int byte = n * 128 + ((kp * 4) ^ swz(n));
      *reinterpret_cast<unsigned*>(reinterpret_cast<char*>(Ws[0]) + byte) =
          cvt_pk_bf16(wlo[it][j], whi[it][j]);
    }
  }

  const int nt = Ka >> 6;
  int cur = 0;
  for (int kt = 0; kt < nt; ++kt) {
    __syncthreads();  // staged tile visible; prior-iter reads of target buf done
    const bool more = (kt + 1) < nt;
    // A-frags direct from global FIRST (so MFMA's vmcnt wait excludes W-next)
    bf8 a[2][4];
#pragma unroll
    for (int ks = 0; ks < 2; ++ks)
#pragma unroll
      for (int mi = 0; mi < 4; ++mi) {
        const int row = wrow + mi * 16 + (lane & 15);
        const int k0 = kt * 64 + ks * 32 + ((lane >> 4) * 8);
        a[ks][mi] = *reinterpret_cast<const bf8*>(Ab + (long)row * ldA + k0);
      }
    // issue next W tile loads (complete during MFMA)
    if (more) {
      const float* Wn = Wb + (long)(kt + 1) * 64 * N;
#pragma unroll
      for (int it = 0; it < 4; ++it) {
        const long k2 = (long)(kp0 + it * 8) * 2;
        wlo[it] = *reinterpret_cast<const f32x4*>(Wn + k2 * N + n0);
        whi[it] = *reinterpret_cast<const f32x4*>(Wn + (k2 + 1) * N + n0);
      }
    }
#pragma unroll
    for (int ks = 0; ks < 2; ++ks) {
      const int kb = ks * 32 + ((lane >> 4) * 8);
      bf8 bfr[8];
#pragma unroll
      for (int ni = 0; ni < 8; ++ni) {
        const int n = ni * 16 + (lane & 15);
        const int byte = n * 128 + ((kb * 2) ^ swz(n));
        bfr[ni] = *reinterpret_cast<const bf8*>(reinterpret_cast<const char*>(Ws[cur]) + byte);
      }
#pragma unroll
      for (int mi = 0; mi < 4; ++mi)
#pragma unroll
        for (int ni = 0; ni < 8; ++ni)
          acc[mi][ni] = __builtin_amdgcn_mfma_f32_16x16x32_bf16(a[ks][mi], bfr[ni], acc[mi][ni], 0, 0, 0);
    }
    // convert+stage next tile into the other buffer (safe: other waves read cur)
    if (more) {
#pragma unroll
      for (int it = 0; it < 4; ++it) {
        const int kp = kp0 + it * 8;
#pragma unroll
        for (int j = 0; j < 4; ++j) {
          const int n = n0 + j;
          const int byte = n * 128 + ((kp * 4) ^ swz(n));
          *reinterpret_cast<unsigned*>(reinterpret_cast<char*>(Ws[cur ^ 1]) + byte) =
              cvt_pk_bf16(wlo[it][j], whi[it][j]);
        }
      }
    }
    cur ^= 1;
  }
  // epilogue: C/D layout col=lane&15, row=(lane>>4)*4+reg
#pragma unroll
  for (int mi = 0; mi < 4; ++mi)
#pragma unroll
    for (int ni = 0; ni < 8; ++ni)
#pragma unroll
      for (int r = 0; r < 4; ++r) {
        int m = wrow + mi * 16 + (lane >> 4) * 4 + r;
        int n = n0blk + ni * 16 + (lane & 15);
        long off = ((long)m * 128 + t) * N + n;
        float v = acc[mi][ni][r];
        if constexpr (OUT_BF16) reinterpret_cast<unsigned short*>(C)[off] = f2bf(v);
        else reinterpret_cast<float*>(C)[off] = v;
      }
}

// ---------------------------------------------------------------------------
// fp32 -> bf16 convert (X)
// ---------------------------------------------------------------------------
__global__ __launch_bounds__(256)
void cvt_bf(const float* __restrict__ in, unsigned short* __restrict__ out, long n)
{
  long i = ((long)blockIdx.x * 256 + threadIdx.x) * 8;
  if (i >= n) return;
  f32x4 a = *reinterpret_cast<const f32x4*>(in + i);
  f32x4 b = *reinterpret_cast<const f32x4*>(in + i + 4);
  u16x4 w0, w1;
#pragma unroll
  for (int j = 0; j < 4; ++j) { w0[j] = f2bf(a[j]); w1[j] = f2bf(b[j]); }
  *reinterpret_cast<u16x4*>(out + i) = w0;
  *reinterpret_cast<u16x4*>(out + i + 4) = w1;
}

// ---------------------------------------------------------------------------
// v (B,T,H*256) -> vT (B*H, 256, 128)   [known-good round-2 path]
// ---------------------------------------------------------------------------
__global__ __launch_bounds__(256)
void trans_v(const unsigned short* __restrict__ vb, unsigned short* __restrict__ vT)
{
  const int bh = blockIdx.y;
  const int b = bh >> 3, h = bh & 7;
  const int tile = blockIdx.x;   // 0..31
  const int tt = tile >> 3;      // t-tile (4)
  const int td = tile & 7;       // d-tile (8)
  __shared__ unsigned short sm[32][33];
  const int rloc = threadIdx.x >> 3;
  const int q4 = (threadIdx.x & 7) * 4;
  {
    long off = ((long)b * 128 + tt * 32 + rloc) * 2048 + h * 256 + td * 32 + q4;
    u16x4 v = *reinterpret_cast<const u16x4*>(vb + off);
#pragma unroll
    for (int j = 0; j < 4; ++j) sm[rloc][q4 + j] = v[j];
  }
  __syncthreads();
  {
    u16x4 w;
#pragma unroll
    for (int j = 0; j < 4; ++j) w[j] = sm[q4 + j][rloc];
    long off = ((long)bh * 256 + td * 32 + rloc) * 128 + tt * 32 + q4;
    *reinterpret_cast<u16x4*>(vT + off) = w;
  }
}

// ---------------------------------------------------------------------------
// Fused attention for one (b,h)  [known-good round-2 version, verbatim]
// ---------------------------------------------------------------------------
__global__ __launch_bounds__(256)
void attn_k(const unsigned short* __restrict__ qg, const unsigned short* __restrict__ kg,
            const unsigned short* __restrict__ vT, unsigned short* __restrict__ cat)
{
  const int h = blockIdx.x, b = blockIdx.y;
  const int tid = threadIdx.x, lane = tid & 63, wv = tid >> 6;
  const int wrow = wv * 32;

  __shared__ short ps[128 * 128];  // P [t][s] swizzled, 32KB (per-wave rows)
  __shared__ short vs[256 * 64];   // vT chunk [d][s_local] swizzled, 32KB

  const long qkBase = ((long)b * 128) * 256 + h * 32;
  const long vBase = ((long)(b * 8 + h)) * 256 * 128;
  const int kb_ = (lane >> 4) * 8;

  // stage vs chunk 0 (s 0..63)
  {
    const int s0 = (tid & 7) * 8;
#pragma unroll
    for (int it = 0; it < 8; ++it) {
      int d = (tid >> 3) + it * 32;
      f32x4 v = *reinterpret_cast<const f32x4*>(vT + vBase + (long)d * 128 + s0);
      int byte = d * 128 + ((s0 * 2) ^ swz(d));
      *reinterpret_cast<f32x4*>(reinterpret_cast<char*>(vs) + byte) = v;
    }
  }

  // S = q k^T  (q/k frags straight from global; AE=32 = one MFMA K-step)
  f32x4 sacc[2][8];
#pragma unroll
  for (int mi = 0; mi < 2; ++mi)
#pragma unroll
    for (int c = 0; c < 8; ++c) sacc[mi][c] = f32x4{0.f, 0.f, 0.f, 0.f};
  bf8 aq[2];
#pragma unroll
  for (int mi = 0; mi < 2; ++mi) {
    int row = wrow + mi * 16 + (lane & 15);
    aq[mi] = *reinterpret_cast<const bf8*>(qg + qkBase + (long)row * 256 + kb_);
  }
#pragma unroll
  for (int ni = 0; ni < 8; ++ni) {
    int s = ni * 16 + (lane & 15);
    bf8 bk = *reinterpret_cast<const bf8*>(kg + qkBase + (long)s * 256 + kb_);
#pragma unroll
    for (int mi = 0; mi < 2; ++mi)
      sacc[mi][ni] = __builtin_amdgcn_mfma_f32_16x16x32_bf16(aq[mi], bk, sacc[mi][ni], 0, 0, 0);
  }

  // wave-parallel softmax; P written unnormalized (divide after PV)
  const float scale = 0.17677669529663687f;  // 1/sqrt(32)
  float sinv[2][4];
#pragma unroll
  for (int mi = 0; mi < 2; ++mi)
#pragma unroll
    for (int r = 0; r < 4; ++r) {
      int row = wrow + mi * 16 + (lane >> 4) * 4 + r;
      float vv[8];
      float mx = -1e30f;
#pragma unroll
      for (int c = 0; c < 8; ++c) { vv[c] = sacc[mi][c][r] * scale; mx = fmaxf(mx, vv[c]); }
#pragma unroll
      for (int mm = 1; mm < 16; mm <<= 1) mx = fmaxf(mx, __shfl_xor(mx, mm, 64));
      float s_ = 0.f;
#pragma unroll
      for (int c = 0; c < 8; ++c) { vv[c] = __expf(vv[c] - mx); s_ += vv[c]; }
#pragma unroll
      for (int mm = 1; mm < 16; mm <<= 1) s_ += __shfl_xor(s_, mm, 64);
      sinv[mi][r] = 1.0f / s_;
#pragma unroll
      for (int c = 0; c < 8; ++c) {
        int col = c * 16 + (lane & 15);
        int byte = row * 256 + ((col * 2) ^ swz(row));
        *reinterpret_cast<unsigned short*>(reinterpret_cast<char*>(ps) + byte) = f2bf(vv[c]);
      }
    }

  // PV over two 64-wide s-chunks
  f32x4 oacc[2][16];
#pragma unroll
  for (int mi = 0; mi < 2; ++mi)
#pragma unroll
    for (int c = 0; c < 16; ++c) oacc[mi][c] = f32x4{0.f, 0.f, 0.f, 0.f};

#pragma unroll 1
  for (int cs = 0; cs < 2; ++cs) {
    if (cs == 1) {
      __syncthreads();  // all waves done with vs chunk 0
      const int s0 = (tid & 7) * 8;
#pragma unroll
      for (int it = 0; it < 8; ++it) {
        int d = (tid >> 3) + it * 32;
        f32x4 v = *reinterpret_cast<const f32x4*>(vT + vBase + (long)d * 128 + 64 + s0);
        int byte = d * 128 + ((s0 * 2) ^ swz(d));
        *reinterpret_cast<f32x4*>(reinterpret_cast<char*>(vs) + byte) = v;
      }
    }
    __syncthreads();  // vs chunk staged
#pragma unroll
    for (int kst = 0; kst < 2; ++kst) {
      int kloc = kst * 32 + kb_;
      int kglob = cs * 64 + kloc;
      bf8 ap[2];
#pragma unroll
      for (int mi = 0; mi < 2; ++mi) {
        int row = wrow + mi * 16 + (lane & 15);
        int byte = row * 256 + ((kglob * 2) ^ swz(row));
        ap[mi] = *reinterpret_cast<const bf8*>(reinterpret_cast<const char*>(ps) + byte);
      }
#pragma unroll
      for (int c = 0; c < 16; ++c) {
        int d = c * 16 + (lane & 15);
        int byte = d * 128 + ((kloc * 2) ^ swz(d));
        bf8 bv = *reinterpret_cast<const bf8*>(reinterpret_cast<const char*>(vs) + byte);
#pragma unroll
        for (int mi = 0; mi < 2; ++mi)
          oacc[mi][c] = __builtin_amdgcn_mfma_f32_16x16x32_bf16(ap[mi], bv, oacc[mi][c], 0, 0, 0);
      }
    }
  }

  // write cat[b,t,h*256+d] = out/row_sum (bf16)
#pragma unroll
  for (int mi = 0; mi < 2; ++mi)
#pragma unroll
    for (int c = 0; c < 16; ++c)
#pragma unroll
      for (int r = 0; r < 4; ++r) {
        int tt = wrow + mi * 16 + (lane >> 4) * 4 + r;
        int d = c * 16 + (lane & 15);
        float v = oacc[mi][c][r] * sinv[mi][r];
        long off = ((long)b * 128 + tt) * 2048 + h * 256 + d;
        cat[off] = f2bf(v);
      }
}

// ---------------------------------------------------------------------------
// LayerNorm(a+b) with gamma/beta; optionally also write bf16 copy.
// ---------------------------------------------------------------------------
template<bool WB>
__global__ __launch_bounds__(256)
void ln_k(const float* __restrict__ a, const float* __restrict__ bsrc,
          const float* __restrict__ gamma, const float* __restrict__ beta,
          float* __restrict__ of, unsigned short* __restrict__ ob)
{
  const int row = blockIdx.x * 4 + (threadIdx.x >> 6);
  const int lane = threadIdx.x & 63;
  const long base = (long)row * 256 + lane * 4;
  f32x4 xa = *reinterpret_cast<const f32x4*>(a + base);
  f32x4 xb = *reinterpret_cast<const f32x4*>(bsrc + base);
  f32x4 x = xa + xb;
  float s = x[0] + x[1] + x[2] + x[3];
  float s2 = x[0] * x[0] + x[1] * x[1] + x[2] * x[2] + x[3] * x[3];
#pragma unroll
  for (int mm = 1; mm < 64; mm <<= 1) { s += __shfl_xor(s, mm, 64); s2 += __shfl_xor(s2, mm, 64); }
  float mean = s * (1.f / 256.f);
  float var = fmaxf(s2 * (1.f / 256.f) - mean * mean, 0.f);
  float inv = rsqrtf(var + 1e-5f);
  f32x4 g = *reinterpret_cast<const f32x4*>(gamma + lane * 4);
  f32x4 be = *reinterpret_cast<const f32x4*>(beta + lane * 4);
  f32x4 y;
#pragma unroll
  for (int j = 0; j < 4; ++j) y[j] = (x[j] - mean) * inv * g[j] + be[j];
  *reinterpret_cast<f32x4*>(of + base) = y;
  if constexpr (WB) {
    u16x4 w;
#pragma unroll
    for (int j = 0; j < 4; ++j) w[j] = f2bf(y[j]);
    *reinterpret_cast<u16x4*>(ob + base) = w;
  }
}

// ---------------------------------------------------------------------------
// hidden = silu(gate) * up  (bf16 in/out)
// ---------------------------------------------------------------------------
__global__ __launch_bounds__(256)
void silu_k(const unsigned short* __restrict__ g, const unsigned short* __restrict__ u,
            unsigned short* __restrict__ o, long n)
{
  long i = ((long)blockIdx.x * 256 + threadIdx.x) * 8;
  if (i >= n) return;
  u16x4 g0 = *reinterpret_cast<const u16x4*>(g + i);
  u16x4 g1 = *reinterpret_cast<const u16x4*>(g + i + 4);
  u16x4 u0 = *reinterpret_cast<const u16x4*>(u + i);
  u16x4 u1 = *reinterpret_cast<const u16x4*>(u + i + 4);
  u16x4 o0, o1;
#pragma unroll
  for (int j = 0; j < 4; ++j) {
    float gg = bf2f(g0[j]), uu = bf2f(u0[j]);
    o0[j] = f2bf(gg / (1.f + __expf(-gg)) * uu);
    gg = bf2f(g1[j]); uu = bf2f(u1[j]);
    o1[j] = f2bf(gg / (1.f + __expf(-gg)) * uu);
  }
  *reinterpret_cast<u16x4*>(o + i) = o0;
  *reinterpret_cast<u16x4*>(o + i + 4) = o1;
}

// ---------------------------------------------------------------------------
// Workspace layout (304 MiB; identical to the round-2 PASS layout):
//   [0,16)   Xb        [16,32) qb       [32,48) kb
//   regA = ws+48MiB, 128MiB:  vb  ->  cat  ->  gate(32)|up(32)|hid(32)
//   regB = ws+176MiB, 128MiB: vT  ->  attnp(32)|x1f(32)|x1b(16)|ffn(32)
// ---------------------------------------------------------------------------
extern "C" void kernel_launch(void* const* d_in, const int* in_sizes, int n_in,
                              void* d_out, int out_size, void* d_ws, size_t ws_size,
                              hipStream_t stream)
{
  const float* X  = (const float*)d_in[0];
  const float* Qw = (const float*)d_in[1];
  const float* Kw = (const float*)d_in[2];
  const float* Vw = (const float*)d_in[3];
  const float* Ow = (const float*)d_in[4];
  const float* Wg = (const float*)d_in[5];
  const float* Wu = (const float*)d_in[6];
  const float* Wd = (const float*)d_in[7];
  const float* g1 = (const float*)d_in[8];
  const float* b1 = (const float*)d_in[9];
  const float* g2 = (const float*)d_in[10];
  const float* b2 = (const float*)d_in[11];

  char* ws = (char*)d_ws;
  const size_t MiB = 1048576;
  unsigned short* Xb = (unsigned short*)(ws);
  unsigned short* qb = (unsigned short*)(ws + 16 * MiB);
  unsigned short* kb = (unsigned short*)(ws + 32 * MiB);
  char* regA = ws + 48 * MiB;    // 128 MiB
  char* regB = regA + 128 * MiB; // 128 MiB

  unsigned short* vb    = (unsigned short*)regA;            // dead after trans_v
  unsigned short* vT    = (unsigned short*)regB;            // dead after attn_k
  unsigned short* cat   = (unsigned short*)regA;            // attn out (vb dead)
  float*          attnp = (float*)(regB);                   // O-proj out (vT dead)
  float*          x1f   = (float*)(regB + 32 * MiB);
  unsigned short* x1b   = (unsigned short*)(regB + 64 * MiB);
  unsigned short* gateb = (unsigned short*)(regA);          // cat dead after O-proj
  unsigned short* upb   = (unsigned short*)(regA + 32 * MiB);
  unsigned short* hidb  = (unsigned short*)(regA + 64 * MiB);
  float*          ffn   = (float*)(regB + 80 * MiB);
  float* out = (float*)d_out;

  dim3 blk(256);
  cvt_bf<<<dim3(4096), blk, 0, stream>>>(X, Xb, (long)8388608);
  gemm_tk<true><<<dim3(2, 128), blk, 0, stream>>>(Xb, Qw, (void*)qb, 256, 256);
  gemm_tk<true><<<dim3(2, 128), blk, 0, stream>>>(Xb, Kw, (void*)kb, 256, 256);
  gemm_tk<true><<<dim3(16, 128), blk, 0, stream>>>(Xb, Vw, (void*)vb, 256, 2048);
  trans_v<<<dim3(32, 2048), blk, 0, stream>>>(vb, vT);
  attn_k<<<dim3(8, 256), blk, 0, stream>>>(qb, kb, vT, cat);
  gemm_tk<false><<<dim3(2, 128), blk, 0, stream>>>(cat, Ow, (void*)attnp, 2048, 256);
  ln_k<true><<<dim3(8192), blk, 0, stream>>>(X, attnp, g1, b1, x1f, x1b);
  gemm_tk<true><<<dim3(4, 128), blk, 0, stream>>>(x1b, Wg, (void*)gateb, 256, 512);
  gemm_tk<true><<<dim3(4, 128), blk, 0, stream>>>(x1b, Wu, (void*)upb, 256, 512);
  silu_k<<<dim3(8192), blk, 0, stream>>>(gateb, upb, hidb, (long)16777216);
  gemm_tk<false><<<dim3(2, 128), blk, 0, stream>>>(hidb, Wd, (void*)ffn, 512, 256);
  ln_k<false><<<dim3(8192), blk, 0, stream>>>(x1f, ffn, g2, b2, out, (unsigned short*)nullptr);
}

// Round 6
// 681.739 us; speedup vs baseline: 1.0080x; 1.0080x over previous
//
#include <hip/hip_runtime.h>
#include <stdint.h>

// Problem constants: B=256, T=128, D=256, H=8, AE=32, DFF=512
#define DEVI static __device__ __forceinline__

typedef __attribute__((ext_vector_type(4))) float f32x4;
typedef __attribute__((ext_vector_type(8))) short bf8;     // 8 bf16 (MFMA A/B frag)
typedef __attribute__((ext_vector_type(4))) unsigned short u16x4;

DEVI unsigned short f2bf(float f) {
  unsigned u = __builtin_bit_cast(unsigned, f);
  u = (u + 0x7FFFu + ((u >> 16) & 1u)) >> 16;
  return (unsigned short)u;
}
DEVI float bf2f(unsigned short s) {
  return __builtin_bit_cast(float, ((unsigned)s) << 16);
}
DEVI unsigned cvt_pk_bf16(float lo, float hi) {
  unsigned r;
  asm("v_cvt_pk_bf16_f32 %0, %1, %2" : "=v"(r) : "v"(lo), "v"(hi));
  return r;
}
// swizzle for 256-B rows (attn ps): 16B granularity, 8 slots
DEVI int swz(int row) { return (((row >> 2) ^ row) & 7) << 4; }
// swizzle for 64-B rows (gemm As/Ws, BK=32): 16B granularity, 4 slots
DEVI int swz32(int row) { return (((row >> 1) ^ row) & 3) << 4; }

DEVI void gload16(const void* g, void* l) {
  __builtin_amdgcn_global_load_lds(
      (const __attribute__((address_space(1))) unsigned*)g,
      (__attribute__((address_space(3))) unsigned*)l, 16, 0, 0);
}

// ---------------------------------------------------------------------------
// Per-t batched GEMM: C[b,t,n] = sum_k A[b,t,k] * W[t,k,n]
// 2-phase pipeline (T3 minimum): dbuf As via global_load_lds (pre-swizzled
// source), dbuf Ws reg-staged fp32->bf16 cvt_pk, ONE barrier per K-tile,
// STAGE(next) issued before compute(cur).  BM=256, BN=128, BK=32, 8 waves.
// Output bitwise-identical to the round-4 PASS version.
// ---------------------------------------------------------------------------
template<bool OUT_BF16>
__global__ __launch_bounds__(512, 4)
void gemm_tk(const unsigned short* __restrict__ A, const float* __restrict__ W,
             void* __restrict__ C, int Ka, int N)
{
  const int t = blockIdx.y;
  const int n0blk = blockIdx.x * 128;
  const int tid = threadIdx.x;
  const int lane = tid & 63;
  const int wv = tid >> 6;        // 0..7
  const int wrow = wv * 32;

  __shared__ short As[2][256 * 32];  // [m][k] 64-B rows, swz32; 2 x 16KB
  __shared__ short Ws[2][128 * 32];  // [n][k] 64-B rows, swz32; 2 x 8KB

  f32x4 acc[2][8];
#pragma unroll
  for (int i = 0; i < 2; ++i)
#pragma unroll
    for (int j = 0; j < 8; ++j) acc[i][j] = f32x4{0.f, 0.f, 0.f, 0.f};

  const long ldA = 128L * Ka;
  const unsigned short* Ab = A + (long)t * Ka;
  const float* Wb = W + (long)t * Ka * N + n0blk;

  const int n0 = (tid & 31) * 4;  // 4 consecutive n per thread (W staging)
  const int kp = tid >> 5;        // k-pair 0..15 (W staging)

  // ---- prologue: stage tile 0 into As[0]/Ws[0]
#pragma unroll
  for (int it = 0; it < 2; ++it) {
    int ci = tid + it * 512;            // 16B chunk id; m=ci>>2
    int m = ci >> 2, cb = (ci & 3) * 16;
    gload16((const char*)(Ab + (long)m * ldA) + (cb ^ swz32(m)),
            (char*)(&As[0][0]) + ci * 16);
  }
  {
    f32x4 wlo = *(const f32x4*)(Wb + (long)(kp * 2) * N + n0);
    f32x4 whi = *(const f32x4*)(Wb + (long)(kp * 2 + 1) * N + n0);
#pragma unroll
    for (int j = 0; j < 4; ++j) {
      int n = n0 + j;
      *(unsigned*)((char*)(&Ws[0][0]) + n * 64 + ((kp * 4) ^ swz32(n))) =
          cvt_pk_bf16(wlo[j], whi[j]);
    }
  }

  const int nt = Ka >> 5;
  int cur = 0;
  for (int kt = 0; kt < nt; ++kt) {
    __syncthreads();  // drain: As[cur]/Ws[cur] ready, prior reads of other buf done
    const bool more = (kt + 1) < nt;
    f32x4 wlo, whi;
    if (more) {
      // STAGE(next) first: loads fly during compute, drained at next barrier
      const unsigned short* An = Ab + (kt + 1) * 32;
#pragma unroll
      for (int it = 0; it < 2; ++it) {
        int ci = tid + it * 512;
        int m = ci >> 2, cb = (ci & 3) * 16;
        gload16((const char*)(An + (long)m * ldA) + (cb ^ swz32(m)),
                (char*)(&As[cur ^ 1][0]) + ci * 16);
      }
      const float* Wn = Wb + (long)(kt + 1) * 32 * N;
      wlo = *(const f32x4*)(Wn + (long)(kp * 2) * N + n0);
      whi = *(const f32x4*)(Wn + (long)(kp * 2 + 1) * N + n0);
    }
    // ---- compute tile kt
    const int kb2 = (lane >> 4) * 16;  // k-chunk byte offset
    bf8 a0, a1;
    {
      const int m0 = wrow + (lane & 15);
      const int m1 = m0 + 16;
      a0 = *(const bf8*)((const char*)(&As[cur][0]) + m0 * 64 + (kb2 ^ swz32(m0)));
      a1 = *(const bf8*)((const char*)(&As[cur][0]) + m1 * 64 + (kb2 ^ swz32(m1)));
    }
#pragma unroll
    for (int ni = 0; ni < 8; ++ni) {
      const int n = ni * 16 + (lane & 15);
      bf8 bfr = *(const bf8*)((const char*)(&Ws[cur][0]) + n * 64 + (kb2 ^ swz32(n)));
      acc[0][ni] = __builtin_amdgcn_mfma_f32_16x16x32_bf16(a0, bfr, acc[0][ni], 0, 0, 0);
      acc[1][ni] = __builtin_amdgcn_mfma_f32_16x16x32_bf16(a1, bfr, acc[1][ni], 0, 0, 0);
    }
    if (more) {
#pragma unroll
      for (int j = 0; j < 4; ++j) {
        int n = n0 + j;
        *(unsigned*)((char*)(&Ws[cur ^ 1][0]) + n * 64 + ((kp * 4) ^ swz32(n))) =
            cvt_pk_bf16(wlo[j], whi[j]);
      }
    }
    cur ^= 1;
  }
  // epilogue: C/D layout col=lane&15, row=(lane>>4)*4+reg
#pragma unroll
  for (int mi = 0; mi < 2; ++mi)
#pragma unroll
    for (int ni = 0; ni < 8; ++ni)
#pragma unroll
      for (int r = 0; r < 4; ++r) {
        int m = wrow + mi * 16 + (lane >> 4) * 4 + r;
        int n = n0blk + ni * 16 + (lane & 15);
        long off = ((long)m * 128 + t) * N + n;
        float v = acc[mi][ni][r];
        if constexpr (OUT_BF16) reinterpret_cast<unsigned short*>(C)[off] = f2bf(v);
        else reinterpret_cast<float*>(C)[off] = v;
      }
}

// ---------------------------------------------------------------------------
// fp32 -> bf16 convert (X)
// ---------------------------------------------------------------------------
__global__ __launch_bounds__(256)
void cvt_bf(const float* __restrict__ in, unsigned short* __restrict__ out, long n)
{
  long i = ((long)blockIdx.x * 256 + threadIdx.x) * 8;
  if (i >= n) return;
  f32x4 a = *reinterpret_cast<const f32x4*>(in + i);
  f32x4 b = *reinterpret_cast<const f32x4*>(in + i + 4);
  u16x4 w0, w1;
#pragma unroll
  for (int j = 0; j < 4; ++j) { w0[j] = f2bf(a[j]); w1[j] = f2bf(b[j]); }
  *reinterpret_cast<u16x4*>(out + i) = w0;
  *reinterpret_cast<u16x4*>(out + i + 4) = w1;
}

// ---------------------------------------------------------------------------
// v (B,T,H*256) -> vT (B*H, 256, 128)   [known-good round-2 path]
// ---------------------------------------------------------------------------
__global__ __launch_bounds__(256)
void trans_v(const unsigned short* __restrict__ vb, unsigned short* __restrict__ vT)
{
  const int bh = blockIdx.y;
  const int b = bh >> 3, h = bh & 7;
  const int tile = blockIdx.x;   // 0..31
  const int tt = tile >> 3;      // t-tile (4)
  const int td = tile & 7;       // d-tile (8)
  __shared__ unsigned short sm[32][33];
  const int rloc = threadIdx.x >> 3;
  const int q4 = (threadIdx.x & 7) * 4;
  {
    long off = ((long)b * 128 + tt * 32 + rloc) * 2048 + h * 256 + td * 32 + q4;
    u16x4 v = *reinterpret_cast<const u16x4*>(vb + off);
#pragma unroll
    for (int j = 0; j < 4; ++j) sm[rloc][q4 + j] = v[j];
  }
  __syncthreads();
  {
    u16x4 w;
#pragma unroll
    for (int j = 0; j < 4; ++j) w[j] = sm[q4 + j][rloc];
    long off = ((long)bh * 256 + td * 32 + rloc) * 128 + tt * 32 + q4;
    *reinterpret_cast<u16x4*>(vT + off) = w;
  }
}

// ---------------------------------------------------------------------------
// Fused attention for one (b,h). Same math/order as the round-2 PASS kernel,
// but V B-frags load DIRECTLY from global vT (16B contiguous per lane,
// L3-resident) — no vs LDS, no barriers (ps rows are wave-private).
// ---------------------------------------------------------------------------
__global__ __launch_bounds__(256)
void attn_k(const unsigned short* __restrict__ qg, const unsigned short* __restrict__ kg,
            const unsigned short* __restrict__ vT, unsigned short* __restrict__ cat)
{
  const int h = blockIdx.x, b = blockIdx.y;
  const int tid = threadIdx.x, lane = tid & 63, wv = tid >> 6;
  const int wrow = wv * 32;

  __shared__ short ps[128 * 128];  // P [t][s] swizzled, 32KB (per-wave rows)

  const long qkBase = ((long)b * 128) * 256 + h * 32;
  const long vBase = ((long)(b * 8 + h)) * 256 * 128;
  const int kb_ = (lane >> 4) * 8;

  // S = q k^T  (q/k frags straight from global; AE=32 = one MFMA K-step)
  f32x4 sacc[2][8];
#pragma unroll
  for (int mi = 0; mi < 2; ++mi)
#pragma unroll
    for (int c = 0; c < 8; ++c) sacc[mi][c] = f32x4{0.f, 0.f, 0.f, 0.f};
  bf8 aq[2];
#pragma unroll
  for (int mi = 0; mi < 2; ++mi) {
    int row = wrow + mi * 16 + (lane & 15);
    aq[mi] = *reinterpret_cast<const bf8*>(qg + qkBase + (long)row * 256 + kb_);
  }
#pragma unroll
  for (int ni = 0; ni < 8; ++ni) {
    int s = ni * 16 + (lane & 15);
    bf8 bk = *reinterpret_cast<const bf8*>(kg + qkBase + (long)s * 256 + kb_);
#pragma unroll
    for (int mi = 0; mi < 2; ++mi)
      sacc[mi][ni] = __builtin_amdgcn_mfma_f32_16x16x32_bf16(aq[mi], bk, sacc[mi][ni], 0, 0, 0);
  }

  // wave-parallel softmax; P written unnormalized (divide after PV)
  const float scale = 0.17677669529663687f;  // 1/sqrt(32)
  float sinv[2][4];
#pragma unroll
  for (int mi = 0; mi < 2; ++mi)
#pragma unroll
    for (int r = 0; r < 4; ++r) {
      int row = wrow + mi * 16 + (lane >> 4) * 4 + r;
      float vv[8];
      float mx = -1e30f;
#pragma unroll
      for (int c = 0; c < 8; ++c) { vv[c] = sacc[mi][c][r] * scale; mx = fmaxf(mx, vv[c]); }
#pragma unroll
      for (int mm = 1; mm < 16; mm <<= 1) mx = fmaxf(mx, __shfl_xor(mx, mm, 64));
      float s_ = 0.f;
#pragma unroll
      for (int c = 0; c < 8; ++c) { vv[c] = __expf(vv[c] - mx); s_ += vv[c]; }
#pragma unroll
      for (int mm = 1; mm < 16; mm <<= 1) s_ += __shfl_xor(s_, mm, 64);
      sinv[mi][r] = 1.0f / s_;
#pragma unroll
      for (int c = 0; c < 8; ++c) {
        int col = c * 16 + (lane & 15);
        int byte = row * 256 + ((col * 2) ^ swz(row));
        *reinterpret_cast<unsigned short*>(reinterpret_cast<char*>(ps) + byte) = f2bf(vv[c]);
      }
    }

  __syncthreads();  // belt-and-braces ordering of ps writes vs frag reads

  // PV: A-frags from ps (own wave's rows), B-frags direct from global vT.
  // k-order kglob = kb_ + {0,32,64,96} == round-2 order -> bitwise identical.
  f32x4 oacc[2][16];
#pragma unroll
  for (int mi = 0; mi < 2; ++mi)
#pragma unroll
    for (int c = 0; c < 16; ++c) oacc[mi][c] = f32x4{0.f, 0.f, 0.f, 0.f};

#pragma unroll
  for (int kst = 0; kst < 4; ++kst) {
    const int kglob = kst * 32 + kb_;
    bf8 ap[2];
#pragma unroll
    for (int mi = 0; mi < 2; ++mi) {
      int row = wrow + mi * 16 + (lane & 15);
      int byte = row * 256 + ((kglob * 2) ^ swz(row));
      ap[mi] = *reinterpret_cast<const bf8*>(reinterpret_cast<const char*>(ps) + byte);
    }
#pragma unroll
    for (int c = 0; c < 16; ++c) {
      int d = c * 16 + (lane & 15);
      bf8 bv = *reinterpret_cast<const bf8*>(vT + vBase + (long)d * 128 + kglob);
#pragma unroll
      for (int mi = 0; mi < 2; ++mi)
        oacc[mi][c] = __builtin_amdgcn_mfma_f32_16x16x32_bf16(ap[mi], bv, oacc[mi][c], 0, 0, 0);
    }
  }

  // write cat[b,t,h*256+d] = out/row_sum (bf16)
#pragma unroll
  for (int mi = 0; mi < 2; ++mi)
#pragma unroll
    for (int c = 0; c < 16; ++c)
#pragma unroll
      for (int r = 0; r < 4; ++r) {
        int tt = wrow + mi * 16 + (lane >> 4) * 4 + r;
        int d = c * 16 + (lane & 15);
        float v = oacc[mi][c][r] * sinv[mi][r];
        long off = ((long)b * 128 + tt) * 2048 + h * 256 + d;
        cat[off] = f2bf(v);
      }
}

// ---------------------------------------------------------------------------
// LayerNorm(a+b) with gamma/beta; optionally also write bf16 copy.
// ---------------------------------------------------------------------------
template<bool WB>
__global__ __launch_bounds__(256)
void ln_k(const float* __restrict__ a, const float* __restrict__ bsrc,
          const float* __restrict__ gamma, const float* __restrict__ beta,
          float* __restrict__ of, unsigned short* __restrict__ ob)
{
  const int row = blockIdx.x * 4 + (threadIdx.x >> 6);
  const int lane = threadIdx.x & 63;
  const long base = (long)row * 256 + lane * 4;
  f32x4 xa = *reinterpret_cast<const f32x4*>(a + base);
  f32x4 xb = *reinterpret_cast<const f32x4*>(bsrc + base);
  f32x4 x = xa + xb;
  float s = x[0] + x[1] + x[2] + x[3];
  float s2 = x[0] * x[0] + x[1] * x[1] + x[2] * x[2] + x[3] * x[3];
#pragma unroll
  for (int mm = 1; mm < 64; mm <<= 1) { s += __shfl_xor(s, mm, 64); s2 += __shfl_xor(s2, mm, 64); }
  float mean = s * (1.f / 256.f);
  float var = fmaxf(s2 * (1.f / 256.f) - mean * mean, 0.f);
  float inv = rsqrtf(var + 1e-5f);
  f32x4 g = *reinterpret_cast<const f32x4*>(gamma + lane * 4);
  f32x4 be = *reinterpret_cast<const f32x4*>(beta + lane * 4);
  f32x4 y;
#pragma unroll
  for (int j = 0; j < 4; ++j) y[j] = (x[j] - mean) * inv * g[j] + be[j];
  *reinterpret_cast<f32x4*>(of + base) = y;
  if constexpr (WB) {
    u16x4 w;
#pragma unroll
    for (int j = 0; j < 4; ++j) w[j] = f2bf(y[j]);
    *reinterpret_cast<u16x4*>(ob + base) = w;
  }
}

// ---------------------------------------------------------------------------
// hidden = silu(gate) * up  (bf16 in/out)
// ---------------------------------------------------------------------------
__global__ __launch_bounds__(256)
void silu_k(const unsigned short* __restrict__ g, const unsigned short* __restrict__ u,
            unsigned short* __restrict__ o, long n)
{
  long i = ((long)blockIdx.x * 256 + threadIdx.x) * 8;
  if (i >= n) return;
  u16x4 g0 = *reinterpret_cast<const u16x4*>(g + i);
  u16x4 g1 = *reinterpret_cast<const u16x4*>(g + i + 4);
  u16x4 u0 = *reinterpret_cast<const u16x4*>(u + i);
  u16x4 u1 = *reinterpret_cast<const u16x4*>(u + i + 4);
  u16x4 o0, o1;
#pragma unroll
  for (int j = 0; j < 4; ++j) {
    float gg = bf2f(g0[j]), uu = bf2f(u0[j]);
    o0[j] = f2bf(gg / (1.f + __expf(-gg)) * uu);
    gg = bf2f(g1[j]); uu = bf2f(u1[j]);
    o1[j] = f2bf(gg / (1.f + __expf(-gg)) * uu);
  }
  *reinterpret_cast<u16x4*>(o + i) = o0;
  *reinterpret_cast<u16x4*>(o + i + 4) = o1;
}

// ---------------------------------------------------------------------------
// Workspace layout (304 MiB; identical to the round-2/4 PASS layout):
//   [0,16)   Xb        [16,32) qb       [32,48) kb
//   regA = ws+48MiB, 128MiB:  vb  ->  cat  ->  gate(32)|up(32)|hid(32)
//   regB = ws+176MiB, 128MiB: vT  ->  attnp(32)|x1f(32)|x1b(16)|ffn(32)
// ---------------------------------------------------------------------------
extern "C" void kernel_launch(void* const* d_in, const int* in_sizes, int n_in,
                              void* d_out, int out_size, void* d_ws, size_t ws_size,
                              hipStream_t stream)
{
  const float* X  = (const float*)d_in[0];
  const float* Qw = (const float*)d_in[1];
  const float* Kw = (const float*)d_in[2];
  const float* Vw = (const float*)d_in[3];
  const float* Ow = (const float*)d_in[4];
  const float* Wg = (const float*)d_in[5];
  const float* Wu = (const float*)d_in[6];
  const float* Wd = (const float*)d_in[7];
  const float* g1 = (const float*)d_in[8];
  const float* b1 = (const float*)d_in[9];
  const float* g2 = (const float*)d_in[10];
  const float* b2 = (const float*)d_in[11];

  char* ws = (char*)d_ws;
  const size_t MiB = 1048576;
  unsigned short* Xb = (unsigned short*)(ws);
  unsigned short* qb = (unsigned short*)(ws + 16 * MiB);
  unsigned short* kb = (unsigned short*)(ws + 32 * MiB);
  char* regA = ws + 48 * MiB;    // 128 MiB
  char* regB = regA + 128 * MiB; // 128 MiB

  unsigned short* vb    = (unsigned short*)regA;            // dead after trans_v
  unsigned short* vT    = (unsigned short*)regB;            // dead after attn_k
  unsigned short* cat   = (unsigned short*)regA;            // attn out (vb dead)
  float*          attnp = (float*)(regB);                   // O-proj out (vT dead)
  float*          x1f   = (float*)(regB + 32 * MiB);
  unsigned short* x1b   = (unsigned short*)(regB + 64 * MiB);
  unsigned short* gateb = (unsigned short*)(regA);          // cat dead after O-proj
  unsigned short* upb   = (unsigned short*)(regA + 32 * MiB);
  unsigned short* hidb  = (unsigned short*)(regA + 64 * MiB);
  float*          ffn   = (float*)(regB + 80 * MiB);
  float* out = (float*)d_out;

  dim3 blk(256), gblk(512);
  cvt_bf<<<dim3(4096), blk, 0, stream>>>(X, Xb, (long)8388608);
  gemm_tk<true><<<dim3(2, 128), gblk, 0, stream>>>(Xb, Qw, (void*)qb, 256, 256);
  gemm_tk<true><<<dim3(2, 128), gblk, 0, stream>>>(Xb, Kw, (void*)kb, 256, 256);
  gemm_tk<true><<<dim3(16, 128), gblk, 0, stream>>>(Xb, Vw, (void*)vb, 256, 2048);
  trans_v<<<dim3(32, 2048), blk, 0, stream>>>(vb, vT);
  attn_k<<<dim3(8, 256), blk, 0, stream>>>(qb, kb, vT, cat);
  gemm_tk<false><<<dim3(2, 128), gblk, 0, stream>>>(cat, Ow, (void*)attnp, 2048, 256);
  ln_k<true><<<dim3(8192), blk, 0, stream>>>(X, attnp, g1, b1, x1f, x1b);
  gemm_tk<true><<<dim3(4, 128), gblk, 0, stream>>>(x1b, Wg, (void*)gateb, 256, 512);
  gemm_tk<true><<<dim3(4, 128), gblk, 0, stream>>>(x1b, Wu, (void*)upb, 256, 512);
  silu_k<<<dim3(8192), blk, 0, stream>>>(gateb, upb, hidb, (long)16777216);
  gemm_tk<false><<<dim3(2, 128), gblk, 0, stream>>>(hidb, Wd, (void*)ffn, 512, 256);
  ln_k<false><<<dim3(8192), blk, 0, stream>>>(x1f, ffn, g2, b2, out, (unsigned short*)nullptr);
}

// Round 7
// 618.754 us; speedup vs baseline: 1.1106x; 1.1018x over previous
//
#include <hip/hip_runtime.h>
#include <stdint.h>

// Problem constants: B=256, T=128, D=256, H=8, AE=32, DFF=512
#define DEVI static __device__ __forceinline__

typedef __attribute__((ext_vector_type(4))) float f32x4;
typedef __attribute__((ext_vector_type(8))) short bf8;     // 8 bf16 (MFMA A/B frag)
typedef __attribute__((ext_vector_type(4))) unsigned short u16x4;

DEVI unsigned short f2bf(float f) {
  unsigned u = __builtin_bit_cast(unsigned, f);
  u = (u + 0x7FFFu + ((u >> 16) & 1u)) >> 16;
  return (unsigned short)u;
}
DEVI float bf2f(unsigned short s) {
  return __builtin_bit_cast(float, ((unsigned)s) << 16);
}
DEVI unsigned cvt_pk_bf16(float lo, float hi) {
  unsigned r;
  asm("v_cvt_pk_bf16_f32 %0, %1, %2" : "=v"(r) : "v"(lo), "v"(hi));
  return r;
}
// swizzle for 256-B rows (attn ps): 16B granularity, 8 slots
DEVI int swz(int row) { return (((row >> 2) ^ row) & 7) << 4; }
// swizzle for 64-B rows (gemm As/Ws, attn vs): 16B granularity, 4 slots
DEVI int swz32(int row) { return (((row >> 1) ^ row) & 3) << 4; }

DEVI void gload16(const void* g, void* l) {
  __builtin_amdgcn_global_load_lds(
      (const __attribute__((address_space(1))) unsigned*)g,
      (__attribute__((address_space(3))) unsigned*)l, 16, 0, 0);
}

// ---------------------------------------------------------------------------
// Per-t batched GEMM: C[b,t,n] = sum_k A[b,t,k] * W[t,k,n]
// 2-phase pipeline (T3 minimum): dbuf As via global_load_lds (pre-swizzled
// source), dbuf Ws reg-staged fp32->bf16 cvt_pk, ONE barrier per K-tile,
// STAGE(next) issued before compute(cur).  BM=256, BN=128, BK=32, 8 waves.
// [unchanged from round 6 — PASS]
// ---------------------------------------------------------------------------
template<bool OUT_BF16>
__global__ __launch_bounds__(512, 4)
void gemm_tk(const unsigned short* __restrict__ A, const float* __restrict__ W,
             void* __restrict__ C, int Ka, int N)
{
  const int t = blockIdx.y;
  const int n0blk = blockIdx.x * 128;
  const int tid = threadIdx.x;
  const int lane = tid & 63;
  const int wv = tid >> 6;        // 0..7
  const int wrow = wv * 32;

  __shared__ short As[2][256 * 32];  // [m][k] 64-B rows, swz32; 2 x 16KB
  __shared__ short Ws[2][128 * 32];  // [n][k] 64-B rows, swz32; 2 x 8KB

  f32x4 acc[2][8];
#pragma unroll
  for (int i = 0; i < 2; ++i)
#pragma unroll
    for (int j = 0; j < 8; ++j) acc[i][j] = f32x4{0.f, 0.f, 0.f, 0.f};

  const long ldA = 128L * Ka;
  const unsigned short* Ab = A + (long)t * Ka;
  const float* Wb = W + (long)t * Ka * N + n0blk;

  const int n0 = (tid & 31) * 4;  // 4 consecutive n per thread (W staging)
  const int kp = tid >> 5;        // k-pair 0..15 (W staging)

  // ---- prologue: stage tile 0 into As[0]/Ws[0]
#pragma unroll
  for (int it = 0; it < 2; ++it) {
    int ci = tid + it * 512;            // 16B chunk id; m=ci>>2
    int m = ci >> 2, cb = (ci & 3) * 16;
    gload16((const char*)(Ab + (long)m * ldA) + (cb ^ swz32(m)),
            (char*)(&As[0][0]) + ci * 16);
  }
  {
    f32x4 wlo = *(const f32x4*)(Wb + (long)(kp * 2) * N + n0);
    f32x4 whi = *(const f32x4*)(Wb + (long)(kp * 2 + 1) * N + n0);
#pragma unroll
    for (int j = 0; j < 4; ++j) {
      int n = n0 + j;
      *(unsigned*)((char*)(&Ws[0][0]) + n * 64 + ((kp * 4) ^ swz32(n))) =
          cvt_pk_bf16(wlo[j], whi[j]);
    }
  }

  const int nt = Ka >> 5;
  int cur = 0;
  for (int kt = 0; kt < nt; ++kt) {
    __syncthreads();  // drain: As[cur]/Ws[cur] ready, prior reads of other buf done
    const bool more = (kt + 1) < nt;
    f32x4 wlo, whi;
    if (more) {
      // STAGE(next) first: loads fly during compute, drained at next barrier
      const unsigned short* An = Ab + (kt + 1) * 32;
#pragma unroll
      for (int it = 0; it < 2; ++it) {
        int ci = tid + it * 512;
        int m = ci >> 2, cb = (ci & 3) * 16;
        gload16((const char*)(An + (long)m * ldA) + (cb ^ swz32(m)),
                (char*)(&As[cur ^ 1][0]) + ci * 16);
      }
      const float* Wn = Wb + (long)(kt + 1) * 32 * N;
      wlo = *(const f32x4*)(Wn + (long)(kp * 2) * N + n0);
      whi = *(const f32x4*)(Wn + (long)(kp * 2 + 1) * N + n0);
    }
    // ---- compute tile kt
    const int kb2 = (lane >> 4) * 16;  // k-chunk byte offset
    bf8 a0, a1;
    {
      const int m0 = wrow + (lane & 15);
      const int m1 = m0 + 16;
      a0 = *(const bf8*)((const char*)(&As[cur][0]) + m0 * 64 + (kb2 ^ swz32(m0)));
      a1 = *(const bf8*)((const char*)(&As[cur][0]) + m1 * 64 + (kb2 ^ swz32(m1)));
    }
#pragma unroll
    for (int ni = 0; ni < 8; ++ni) {
      const int n = ni * 16 + (lane & 15);
      bf8 bfr = *(const bf8*)((const char*)(&Ws[cur][0]) + n * 64 + (kb2 ^ swz32(n)));
      acc[0][ni] = __builtin_amdgcn_mfma_f32_16x16x32_bf16(a0, bfr, acc[0][ni], 0, 0, 0);
      acc[1][ni] = __builtin_amdgcn_mfma_f32_16x16x32_bf16(a1, bfr, acc[1][ni], 0, 0, 0);
    }
    if (more) {
#pragma unroll
      for (int j = 0; j < 4; ++j) {
        int n = n0 + j;
        *(unsigned*)((char*)(&Ws[cur ^ 1][0]) + n * 64 + ((kp * 4) ^ swz32(n))) =
            cvt_pk_bf16(wlo[j], whi[j]);
      }
    }
    cur ^= 1;
  }
  // epilogue: C/D layout col=lane&15, row=(lane>>4)*4+reg
#pragma unroll
  for (int mi = 0; mi < 2; ++mi)
#pragma unroll
    for (int ni = 0; ni < 8; ++ni)
#pragma unroll
      for (int r = 0; r < 4; ++r) {
        int m = wrow + mi * 16 + (lane >> 4) * 4 + r;
        int n = n0blk + ni * 16 + (lane & 15);
        long off = ((long)m * 128 + t) * N + n;
        float v = acc[mi][ni][r];
        if constexpr (OUT_BF16) reinterpret_cast<unsigned short*>(C)[off] = f2bf(v);
        else reinterpret_cast<float*>(C)[off] = v;
      }
}

// ---------------------------------------------------------------------------
// fp32 -> bf16 convert (X)
// ---------------------------------------------------------------------------
__global__ __launch_bounds__(256)
void cvt_bf(const float* __restrict__ in, unsigned short* __restrict__ out, long n)
{
  long i = ((long)blockIdx.x * 256 + threadIdx.x) * 8;
  if (i >= n) return;
  f32x4 a = *reinterpret_cast<const f32x4*>(in + i);
  f32x4 b = *reinterpret_cast<const f32x4*>(in + i + 4);
  u16x4 w0, w1;
#pragma unroll
  for (int j = 0; j < 4; ++j) { w0[j] = f2bf(a[j]); w1[j] = f2bf(b[j]); }
  *reinterpret_cast<u16x4*>(out + i) = w0;
  *reinterpret_cast<u16x4*>(out + i + 4) = w1;
}

// ---------------------------------------------------------------------------
// v (B,T,H*256) -> vT (B*H, 256, 128)   [known-good]
// ---------------------------------------------------------------------------
__global__ __launch_bounds__(256)
void trans_v(const unsigned short* __restrict__ vb, unsigned short* __restrict__ vT)
{
  const int bh = blockIdx.y;
  const int b = bh >> 3, h = bh & 7;
  const int tile = blockIdx.x;   // 0..31
  const int tt = tile >> 3;      // t-tile (4)
  const int td = tile & 7;       // d-tile (8)
  __shared__ unsigned short sm[32][33];
  const int rloc = threadIdx.x >> 3;
  const int q4 = (threadIdx.x & 7) * 4;
  {
    long off = ((long)b * 128 + tt * 32 + rloc) * 2048 + h * 256 + td * 32 + q4;
    u16x4 v = *reinterpret_cast<const u16x4*>(vb + off);
#pragma unroll
    for (int j = 0; j < 4; ++j) sm[rloc][q4 + j] = v[j];
  }
  __syncthreads();
  {
    u16x4 w;
#pragma unroll
    for (int j = 0; j < 4; ++j) w[j] = sm[q4 + j][rloc];
    long off = ((long)bh * 256 + td * 32 + rloc) * 128 + tt * 32 + q4;
    *reinterpret_cast<u16x4*>(vT + off) = w;
  }
}

// ---------------------------------------------------------------------------
// Fused attention for one (b,h). Round-6 math (bitwise identical output).
// NEW: V staged into LDS via global_load_lds with PRE-SWIZZLED SOURCE
// (m173 pattern): 4 s-chunks of 16KB, double-buffered; STAGE(cs+1) issued
// after the barrier, before compute(cs)  [T3 minimum recipe].
// PV B-frags from LDS (64-B rows, swz32 -> 2-way conflict = free).
// ---------------------------------------------------------------------------
__global__ __launch_bounds__(256)
void attn_k(const unsigned short* __restrict__ qg, const unsigned short* __restrict__ kg,
            const unsigned short* __restrict__ vT, unsigned short* __restrict__ cat)
{
  const int h = blockIdx.x, b = blockIdx.y;
  const int tid = threadIdx.x, lane = tid & 63, wv = tid >> 6;
  const int wrow = wv * 32;

  __shared__ short ps[128 * 128];    // P [t][s] swizzled (256-B rows), 32KB
  __shared__ short vs[2][256 * 32];  // vT s-chunk [d][s32] 64-B rows swz32, 2x16KB

  const long qkBase = ((long)b * 128) * 256 + h * 32;
  const long vBase = ((long)(b * 8 + h)) * 256 * 128;
  const int kb_ = (lane >> 4) * 8;

  // stage s-chunk 0 into vs[0] (issue-only; drained at first barrier).
  // chunk ci: d=ci>>2, sc=ci&3; dest byte = ci*16 (linear = wave base + lane*16);
  // src elem = vBase + d*128 + cs*32 + (((sc*16)^swz32(d))>>1)  [inverse-swz src]
#pragma unroll
  for (int it = 0; it < 4; ++it) {
    int ci = tid + it * 256;
    int d = ci >> 2, sc = ci & 3;
    gload16(vT + vBase + (long)d * 128 + (((sc * 16) ^ swz32(d)) >> 1),
            (char*)(&vs[0][0]) + ci * 16);
  }

  // S = q k^T  (q/k frags straight from global; AE=32 = one MFMA K-step)
  f32x4 sacc[2][8];
#pragma unroll
  for (int mi = 0; mi < 2; ++mi)
#pragma unroll
    for (int c = 0; c < 8; ++c) sacc[mi][c] = f32x4{0.f, 0.f, 0.f, 0.f};
  bf8 aq[2];
#pragma unroll
  for (int mi = 0; mi < 2; ++mi) {
    int row = wrow + mi * 16 + (lane & 15);
    aq[mi] = *reinterpret_cast<const bf8*>(qg + qkBase + (long)row * 256 + kb_);
  }
#pragma unroll
  for (int ni = 0; ni < 8; ++ni) {
    int s = ni * 16 + (lane & 15);
    bf8 bk = *reinterpret_cast<const bf8*>(kg + qkBase + (long)s * 256 + kb_);
#pragma unroll
    for (int mi = 0; mi < 2; ++mi)
      sacc[mi][ni] = __builtin_amdgcn_mfma_f32_16x16x32_bf16(aq[mi], bk, sacc[mi][ni], 0, 0, 0);
  }

  // wave-parallel softmax; P written unnormalized (divide after PV)
  const float scale = 0.17677669529663687f;  // 1/sqrt(32)
  float sinv[2][4];
#pragma unroll
  for (int mi = 0; mi < 2; ++mi)
#pragma unroll
    for (int r = 0; r < 4; ++r) {
      int row = wrow + mi * 16 + (lane >> 4) * 4 + r;
      float vv[8];
      float mx = -1e30f;
#pragma unroll
      for (int c = 0; c < 8; ++c) { vv[c] = sacc[mi][c][r] * scale; mx = fmaxf(mx, vv[c]); }
#pragma unroll
      for (int mm = 1; mm < 16; mm <<= 1) mx = fmaxf(mx, __shfl_xor(mx, mm, 64));
      float s_ = 0.f;
#pragma unroll
      for (int c = 0; c < 8; ++c) { vv[c] = __expf(vv[c] - mx); s_ += vv[c]; }
#pragma unroll
      for (int mm = 1; mm < 16; mm <<= 1) s_ += __shfl_xor(s_, mm, 64);
      sinv[mi][r] = 1.0f / s_;
#pragma unroll
      for (int c = 0; c < 8; ++c) {
        int col = c * 16 + (lane & 15);
        int byte = row * 256 + ((col * 2) ^ swz(row));
        *reinterpret_cast<unsigned short*>(reinterpret_cast<char*>(ps) + byte) = f2bf(vv[c]);
      }
    }

  // PV over four 32-wide s-chunks, double-buffered LDS; same k-order as
  // round 6 (kglob = cs*32 + kb_) -> bitwise-identical oacc.
  f32x4 oacc[2][16];
#pragma unroll
  for (int mi = 0; mi < 2; ++mi)
#pragma unroll
    for (int c = 0; c < 16; ++c) oacc[mi][c] = f32x4{0.f, 0.f, 0.f, 0.f};

#pragma unroll 1
  for (int cs = 0; cs < 4; ++cs) {
    __syncthreads();  // vs[cs&1] staged (vmcnt drained); cs-1 compute done
    if (cs < 3) {
      // STAGE next chunk into the other buffer; overlaps this chunk's MFMAs
#pragma unroll
      for (int it = 0; it < 4; ++it) {
        int ci = tid + it * 256;
        int d = ci >> 2, sc = ci & 3;
        gload16(vT + vBase + (long)d * 128 + (cs + 1) * 32 + (((sc * 16) ^ swz32(d)) >> 1),
                (char*)(&vs[(cs + 1) & 1][0]) + ci * 16);
      }
    }
    const int kglob = cs * 32 + kb_;
    bf8 ap[2];
#pragma unroll
    for (int mi = 0; mi < 2; ++mi) {
      int row = wrow + mi * 16 + (lane & 15);
      int byte = row * 256 + ((kglob * 2) ^ swz(row));
      ap[mi] = *reinterpret_cast<const bf8*>(reinterpret_cast<const char*>(ps) + byte);
    }
    __builtin_amdgcn_s_setprio(1);
#pragma unroll
    for (int c = 0; c < 16; ++c) {
      int d = c * 16 + (lane & 15);
      bf8 bv = *reinterpret_cast<const bf8*>(
          reinterpret_cast<const char*>(&vs[cs & 1][0]) + d * 64 + ((kb_ * 2) ^ swz32(d)));
#pragma unroll
      for (int mi = 0; mi < 2; ++mi)
        oacc[mi][c] = __builtin_amdgcn_mfma_f32_16x16x32_bf16(ap[mi], bv, oacc[mi][c], 0, 0, 0);
    }
    __builtin_amdgcn_s_setprio(0);
  }

  // write cat[b,t,h*256+d] = out/row_sum (bf16)
#pragma unroll
  for (int mi = 0; mi < 2; ++mi)
#pragma unroll
    for (int c = 0; c < 16; ++c)
#pragma unroll
      for (int r = 0; r < 4; ++r) {
        int tt = wrow + mi * 16 + (lane >> 4) * 4 + r;
        int d = c * 16 + (lane & 15);
        float v = oacc[mi][c][r] * sinv[mi][r];
        long off = ((long)b * 128 + tt) * 2048 + h * 256 + d;
        cat[off] = f2bf(v);
      }
}

// ---------------------------------------------------------------------------
// LayerNorm(a+b) with gamma/beta; optionally also write bf16 copy.
// ---------------------------------------------------------------------------
template<bool WB>
__global__ __launch_bounds__(256)
void ln_k(const float* __restrict__ a, const float* __restrict__ bsrc,
          const float* __restrict__ gamma, const float* __restrict__ beta,
          float* __restrict__ of, unsigned short* __restrict__ ob)
{
  const int row = blockIdx.x * 4 + (threadIdx.x >> 6);
  const int lane = threadIdx.x & 63;
  const long base = (long)row * 256 + lane * 4;
  f32x4 xa = *reinterpret_cast<const f32x4*>(a + base);
  f32x4 xb = *reinterpret_cast<const f32x4*>(bsrc + base);
  f32x4 x = xa + xb;
  float s = x[0] + x[1] + x[2] + x[3];
  float s2 = x[0] * x[0] + x[1] * x[1] + x[2] * x[2] + x[3] * x[3];
#pragma unroll
  for (int mm = 1; mm < 64; mm <<= 1) { s += __shfl_xor(s, mm, 64); s2 += __shfl_xor(s2, mm, 64); }
  float mean = s * (1.f / 256.f);
  float var = fmaxf(s2 * (1.f / 256.f) - mean * mean, 0.f);
  float inv = rsqrtf(var + 1e-5f);
  f32x4 g = *reinterpret_cast<const f32x4*>(gamma + lane * 4);
  f32x4 be = *reinterpret_cast<const f32x4*>(beta + lane * 4);
  f32x4 y;
#pragma unroll
  for (int j = 0; j < 4; ++j) y[j] = (x[j] - mean) * inv * g[j] + be[j];
  *reinterpret_cast<f32x4*>(of + base) = y;
  if constexpr (WB) {
    u16x4 w;
#pragma unroll
    for (int j = 0; j < 4; ++j) w[j] = f2bf(y[j]);
    *reinterpret_cast<u16x4*>(ob + base) = w;
  }
}

// ---------------------------------------------------------------------------
// hidden = silu(gate) * up  (bf16 in/out)
// ---------------------------------------------------------------------------
__global__ __launch_bounds__(256)
void silu_k(const unsigned short* __restrict__ g, const unsigned short* __restrict__ u,
            unsigned short* __restrict__ o, long n)
{
  long i = ((long)blockIdx.x * 256 + threadIdx.x) * 8;
  if (i >= n) return;
  u16x4 g0 = *reinterpret_cast<const u16x4*>(g + i);
  u16x4 g1 = *reinterpret_cast<const u16x4*>(g + i + 4);
  u16x4 u0 = *reinterpret_cast<const u16x4*>(u + i);
  u16x4 u1 = *reinterpret_cast<const u16x4*>(u + i + 4);
  u16x4 o0, o1;
#pragma unroll
  for (int j = 0; j < 4; ++j) {
    float gg = bf2f(g0[j]), uu = bf2f(u0[j]);
    o0[j] = f2bf(gg / (1.f + __expf(-gg)) * uu);
    gg = bf2f(g1[j]); uu = bf2f(u1[j]);
    o1[j] = f2bf(gg / (1.f + __expf(-gg)) * uu);
  }
  *reinterpret_cast<u16x4*>(o + i) = o0;
  *reinterpret_cast<u16x4*>(o + i + 4) = o1;
}

// ---------------------------------------------------------------------------
// Workspace layout (304 MiB; identical to the round-2/4/6 PASS layout):
//   [0,16)   Xb        [16,32) qb       [32,48) kb
//   regA = ws+48MiB, 128MiB:  vb  ->  cat  ->  gate(32)|up(32)|hid(32)
//   regB = ws+176MiB, 128MiB: vT  ->  attnp(32)|x1f(32)|x1b(16)|ffn(32)
// ---------------------------------------------------------------------------
extern "C" void kernel_launch(void* const* d_in, const int* in_sizes, int n_in,
                              void* d_out, int out_size, void* d_ws, size_t ws_size,
                              hipStream_t stream)
{
  const float* X  = (const float*)d_in[0];
  const float* Qw = (const float*)d_in[1];
  const float* Kw = (const float*)d_in[2];
  const float* Vw = (const float*)d_in[3];
  const float* Ow = (const float*)d_in[4];
  const float* Wg = (const float*)d_in[5];
  const float* Wu = (const float*)d_in[6];
  const float* Wd = (const float*)d_in[7];
  const float* g1 = (const float*)d_in[8];
  const float* b1 = (const float*)d_in[9];
  const float* g2 = (const float*)d_in[10];
  const float* b2 = (const float*)d_in[11];

  char* ws = (char*)d_ws;
  const size_t MiB = 1048576;
  unsigned short* Xb = (unsigned short*)(ws);
  unsigned short* qb = (unsigned short*)(ws + 16 * MiB);
  unsigned short* kb = (unsigned short*)(ws + 32 * MiB);
  char* regA = ws + 48 * MiB;    // 128 MiB
  char* regB = regA + 128 * MiB; // 128 MiB

  unsigned short* vb    = (unsigned short*)regA;            // dead after trans_v
  unsigned short* vT    = (unsigned short*)regB;            // dead after attn_k
  unsigned short* cat   = (unsigned short*)regA;            // attn out (vb dead)
  float*          attnp = (float*)(regB);                   // O-proj out (vT dead)
  float*          x1f   = (float*)(regB + 32 * MiB);
  unsigned short* x1b   = (unsigned short*)(regB + 64 * MiB);
  unsigned short* gateb = (unsigned short*)(regA);          // cat dead after O-proj
  unsigned short* upb   = (unsigned short*)(regA + 32 * MiB);
  unsigned short* hidb  = (unsigned short*)(regA + 64 * MiB);
  float*          ffn   = (float*)(regB + 80 * MiB);
  float* out = (float*)d_out;

  dim3 blk(256), gblk(512);
  cvt_bf<<<dim3(4096), blk, 0, stream>>>(X, Xb, (long)8388608);
  gemm_tk<true><<<dim3(2, 128), gblk, 0, stream>>>(Xb, Qw, (void*)qb, 256, 256);
  gemm_tk<true><<<dim3(2, 128), gblk, 0, stream>>>(Xb, Kw, (void*)kb, 256, 256);
  gemm_tk<true><<<dim3(16, 128), gblk, 0, stream>>>(Xb, Vw, (void*)vb, 256, 2048);
  trans_v<<<dim3(32, 2048), blk, 0, stream>>>(vb, vT);
  attn_k<<<dim3(8, 256), blk, 0, stream>>>(qb, kb, vT, cat);
  gemm_tk<false><<<dim3(2, 128), gblk, 0, stream>>>(cat, Ow, (void*)attnp, 2048, 256);
  ln_k<true><<<dim3(8192), blk, 0, stream>>>(X, attnp, g1, b1, x1f, x1b);
  gemm_tk<true><<<dim3(4, 128), gblk, 0, stream>>>(x1b, Wg, (void*)gateb, 256, 512);
  gemm_tk<true><<<dim3(4, 128), gblk, 0, stream>>>(x1b, Wu, (void*)upb, 256, 512);
  silu_k<<<dim3(8192), blk, 0, stream>>>(gateb, upb, hidb, (long)16777216);
  gemm_tk<false><<<dim3(2, 128), gblk, 0, stream>>>(hidb, Wd, (void*)ffn, 512, 256);
  ln_k<false><<<dim3(8192), blk, 0, stream>>>(x1f, ffn, g2, b2, out, (unsigned short*)nullptr);
}

// Round 8
// 587.211 us; speedup vs baseline: 1.1703x; 1.0537x over previous
//
#include <hip/hip_runtime.h>
#include <stdint.h>

// Problem constants: B=256, T=128, D=256, H=8, AE=32, DFF=512
#define DEVI static __device__ __forceinline__

typedef __attribute__((ext_vector_type(4))) float f32x4;
typedef __attribute__((ext_vector_type(8))) short bf8;     // 8 bf16 (MFMA A/B frag)
typedef __attribute__((ext_vector_type(4))) unsigned short u16x4;

DEVI unsigned short f2bf(float f) {
  unsigned u = __builtin_bit_cast(unsigned, f);
  u = (u + 0x7FFFu + ((u >> 16) & 1u)) >> 16;
  return (unsigned short)u;
}
DEVI float bf2f(unsigned short s) {
  return __builtin_bit_cast(float, ((unsigned)s) << 16);
}
DEVI unsigned cvt_pk_bf16(float lo, float hi) {
  unsigned r;
  asm("v_cvt_pk_bf16_f32 %0, %1, %2" : "=v"(r) : "v"(lo), "v"(hi));
  return r;
}
// swizzle for 256-B rows (attn ps): 16B granularity, 8 slots
DEVI int swz(int row) { return (((row >> 2) ^ row) & 7) << 4; }
// swizzle for 64-B rows (gemm As/Ws, attn vs): 16B granularity, 4 slots
DEVI int swz32(int row) { return (((row >> 1) ^ row) & 3) << 4; }

DEVI void gload16(const void* g, void* l) {
  __builtin_amdgcn_global_load_lds(
      (const __attribute__((address_space(1))) unsigned*)g,
      (__attribute__((address_space(3))) unsigned*)l, 16, 0, 0);
}

// ---------------------------------------------------------------------------
// Per-t batched GEMM: C[b,t, n0+*] = sum_k A[b,t,k] * Wsel[t,k,n]
// 2-phase pipeline (T3): dbuf As via global_load_lds (pre-swizzled source),
// dbuf Ws reg-staged fp32->bf16 cvt_pk, ONE barrier per K-tile, STAGE(next)
// before compute(cur). BM=256, BN=128, BK=32, 8 waves. [data path = round-7 PASS]
// NEW (round 8, index-remap only):
//  - 1-D grid, XCD same-t grouping: t=(j&7)+8*(j>>(3+lognx)), n=(j>>3)&(nx-1)
//    -> all n-blocks of one t share an XCD (bid%8) -> A-slice L2-deduped.
//  - two-weight fusion: n0blk >= N selects W1 (e.g. Q|K, gate|up); C written
//    at row stride ldC with global column n0blk.
// ---------------------------------------------------------------------------
template<bool OUT_BF16>
__global__ __launch_bounds__(512, 4)
void gemm_tk(const unsigned short* __restrict__ A, const float* __restrict__ W0,
             const float* __restrict__ W1, void* __restrict__ C,
             int Ka, int N, int lognx, int ldC)
{
  const int j = blockIdx.x;
  const int t = (j & 7) + ((j >> (3 + lognx)) << 3);
  const int nblk = (j >> 3) & ((1 << lognx) - 1);
  const int n0blk = nblk * 128;
  const float* Wsel = (n0blk >= N) ? W1 : W0;
  const int n0w = (n0blk >= N) ? (n0blk - N) : n0blk;

  const int tid = threadIdx.x;
  const int lane = tid & 63;
  const int wv = tid >> 6;        // 0..7
  const int wrow = wv * 32;

  __shared__ short As[2][256 * 32];  // [m][k] 64-B rows, swz32; 2 x 16KB
  __shared__ short Ws[2][128 * 32];  // [n][k] 64-B rows, swz32; 2 x 8KB

  f32x4 acc[2][8];
#pragma unroll
  for (int i = 0; i < 2; ++i)
#pragma unroll
    for (int jj = 0; jj < 8; ++jj) acc[i][jj] = f32x4{0.f, 0.f, 0.f, 0.f};

  const long ldA = 128L * Ka;
  const unsigned short* Ab = A + (long)t * Ka;
  const float* Wb = Wsel + (long)t * Ka * N + n0w;

  const int n0 = (tid & 31) * 4;  // 4 consecutive n per thread (W staging)
  const int kp = tid >> 5;        // k-pair 0..15 (W staging)

  // ---- prologue: stage tile 0 into As[0]/Ws[0]
#pragma unroll
  for (int it = 0; it < 2; ++it) {
    int ci = tid + it * 512;            // 16B chunk id; m=ci>>2
    int m = ci >> 2, cb = (ci & 3) * 16;
    gload16((const char*)(Ab + (long)m * ldA) + (cb ^ swz32(m)),
            (char*)(&As[0][0]) + ci * 16);
  }
  {
    f32x4 wlo = *(const f32x4*)(Wb + (long)(kp * 2) * N + n0);
    f32x4 whi = *(const f32x4*)(Wb + (long)(kp * 2 + 1) * N + n0);
#pragma unroll
    for (int jj = 0; jj < 4; ++jj) {
      int n = n0 + jj;
      *(unsigned*)((char*)(&Ws[0][0]) + n * 64 + ((kp * 4) ^ swz32(n))) =
          cvt_pk_bf16(wlo[jj], whi[jj]);
    }
  }

  const int nt = Ka >> 5;
  int cur = 0;
  for (int kt = 0; kt < nt; ++kt) {
    __syncthreads();  // drain: As[cur]/Ws[cur] ready, prior reads of other buf done
    const bool more = (kt + 1) < nt;
    f32x4 wlo, whi;
    if (more) {
      // STAGE(next) first: loads fly during compute, drained at next barrier
      const unsigned short* An = Ab + (kt + 1) * 32;
#pragma unroll
      for (int it = 0; it < 2; ++it) {
        int ci = tid + it * 512;
        int m = ci >> 2, cb = (ci & 3) * 16;
        gload16((const char*)(An + (long)m * ldA) + (cb ^ swz32(m)),
                (char*)(&As[cur ^ 1][0]) + ci * 16);
      }
      const float* Wn = Wb + (long)(kt + 1) * 32 * N;
      wlo = *(const f32x4*)(Wn + (long)(kp * 2) * N + n0);
      whi = *(const f32x4*)(Wn + (long)(kp * 2 + 1) * N + n0);
    }
    // ---- compute tile kt
    const int kb2 = (lane >> 4) * 16;  // k-chunk byte offset
    bf8 a0, a1;
    {
      const int m0 = wrow + (lane & 15);
      const int m1 = m0 + 16;
      a0 = *(const bf8*)((const char*)(&As[cur][0]) + m0 * 64 + (kb2 ^ swz32(m0)));
      a1 = *(const bf8*)((const char*)(&As[cur][0]) + m1 * 64 + (kb2 ^ swz32(m1)));
    }
#pragma unroll
    for (int ni = 0; ni < 8; ++ni) {
      const int n = ni * 16 + (lane & 15);
      bf8 bfr = *(const bf8*)((const char*)(&Ws[cur][0]) + n * 64 + (kb2 ^ swz32(n)));
      acc[0][ni] = __builtin_amdgcn_mfma_f32_16x16x32_bf16(a0, bfr, acc[0][ni], 0, 0, 0);
      acc[1][ni] = __builtin_amdgcn_mfma_f32_16x16x32_bf16(a1, bfr, acc[1][ni], 0, 0, 0);
    }
    if (more) {
#pragma unroll
      for (int jj = 0; jj < 4; ++jj) {
        int n = n0 + jj;
        *(unsigned*)((char*)(&Ws[cur ^ 1][0]) + n * 64 + ((kp * 4) ^ swz32(n))) =
            cvt_pk_bf16(wlo[jj], whi[jj]);
      }
    }
    cur ^= 1;
  }
  // epilogue: C/D layout col=lane&15, row=(lane>>4)*4+reg
#pragma unroll
  for (int mi = 0; mi < 2; ++mi)
#pragma unroll
    for (int ni = 0; ni < 8; ++ni)
#pragma unroll
      for (int r = 0; r < 4; ++r) {
        int m = wrow + mi * 16 + (lane >> 4) * 4 + r;
        int n = n0blk + ni * 16 + (lane & 15);
        long off = ((long)m * 128 + t) * ldC + n;
        float v = acc[mi][ni][r];
        if constexpr (OUT_BF16) reinterpret_cast<unsigned short*>(C)[off] = f2bf(v);
        else reinterpret_cast<float*>(C)[off] = v;
      }
}

// ---------------------------------------------------------------------------
// fp32 -> bf16 convert (X)
// ---------------------------------------------------------------------------
__global__ __launch_bounds__(256)
void cvt_bf(const float* __restrict__ in, unsigned short* __restrict__ out, long n)
{
  long i = ((long)blockIdx.x * 256 + threadIdx.x) * 8;
  if (i >= n) return;
  f32x4 a = *reinterpret_cast<const f32x4*>(in + i);
  f32x4 b = *reinterpret_cast<const f32x4*>(in + i + 4);
  u16x4 w0, w1;
#pragma unroll
  for (int j = 0; j < 4; ++j) { w0[j] = f2bf(a[j]); w1[j] = f2bf(b[j]); }
  *reinterpret_cast<u16x4*>(out + i) = w0;
  *reinterpret_cast<u16x4*>(out + i + 4) = w1;
}

// ---------------------------------------------------------------------------
// v (B,T,H*256) -> vT (B*H, 256, 128)   [known-good]
// ---------------------------------------------------------------------------
__global__ __launch_bounds__(256)
void trans_v(const unsigned short* __restrict__ vb, unsigned short* __restrict__ vT)
{
  const int bh = blockIdx.y;
  const int b = bh >> 3, h = bh & 7;
  const int tile = blockIdx.x;   // 0..31
  const int tt = tile >> 3;      // t-tile (4)
  const int td = tile & 7;       // d-tile (8)
  __shared__ unsigned short sm[32][33];
  const int rloc = threadIdx.x >> 3;
  const int q4 = (threadIdx.x & 7) * 4;
  {
    long off = ((long)b * 128 + tt * 32 + rloc) * 2048 + h * 256 + td * 32 + q4;
    u16x4 v = *reinterpret_cast<const u16x4*>(vb + off);
#pragma unroll
    for (int j = 0; j < 4; ++j) sm[rloc][q4 + j] = v[j];
  }
  __syncthreads();
  {
    u16x4 w;
#pragma unroll
    for (int j = 0; j < 4; ++j) w[j] = sm[q4 + j][rloc];
    long off = ((long)bh * 256 + td * 32 + rloc) * 128 + tt * 32 + q4;
    *reinterpret_cast<u16x4*>(vT + off) = w;
  }
}

// ---------------------------------------------------------------------------
// Fused attention for one (b,h). [round-7 PASS data path; only q/k now come
// from the fused qkb buffer: row stride 512, k at column offset 256]
// ---------------------------------------------------------------------------
__global__ __launch_bounds__(256)
void attn_k(const unsigned short* __restrict__ qk, const unsigned short* __restrict__ vT,
            unsigned short* __restrict__ cat)
{
  const int h = blockIdx.x, b = blockIdx.y;
  const int tid = threadIdx.x, lane = tid & 63, wv = tid >> 6;
  const int wrow = wv * 32;

  __shared__ short ps[128 * 128];    // P [t][s] swizzled (256-B rows), 32KB
  __shared__ short vs[2][256 * 32];  // vT s-chunk [d][s32] 64-B rows swz32, 2x16KB

  const long qkBase = ((long)b * 128) * 512 + h * 32;
  const long vBase = ((long)(b * 8 + h)) * 256 * 128;
  const int kb_ = (lane >> 4) * 8;

  // stage s-chunk 0 into vs[0] (issue-only; drained at first barrier).
#pragma unroll
  for (int it = 0; it < 4; ++it) {
    int ci = tid + it * 256;
    int d = ci >> 2, sc = ci & 3;
    gload16(vT + vBase + (long)d * 128 + (((sc * 16) ^ swz32(d)) >> 1),
            (char*)(&vs[0][0]) + ci * 16);
  }

  // S = q k^T  (q/k frags straight from global; AE=32 = one MFMA K-step)
  f32x4 sacc[2][8];
#pragma unroll
  for (int mi = 0; mi < 2; ++mi)
#pragma unroll
    for (int c = 0; c < 8; ++c) sacc[mi][c] = f32x4{0.f, 0.f, 0.f, 0.f};
  bf8 aq[2];
#pragma unroll
  for (int mi = 0; mi < 2; ++mi) {
    int row = wrow + mi * 16 + (lane & 15);
    aq[mi] = *reinterpret_cast<const bf8*>(qk + qkBase + (long)row * 512 + kb_);
  }
#pragma unroll
  for (int ni = 0; ni < 8; ++ni) {
    int s = ni * 16 + (lane & 15);
    bf8 bk = *reinterpret_cast<const bf8*>(qk + qkBase + 256 + (long)s * 512 + kb_);
#pragma unroll
    for (int mi = 0; mi < 2; ++mi)
      sacc[mi][ni] = __builtin_amdgcn_mfma_f32_16x16x32_bf16(aq[mi], bk, sacc[mi][ni], 0, 0, 0);
  }

  // wave-parallel softmax; P written unnormalized (divide after PV)
  const float scale = 0.17677669529663687f;  // 1/sqrt(32)
  float sinv[2][4];
#pragma unroll
  for (int mi = 0; mi < 2; ++mi)
#pragma unroll
    for (int r = 0; r < 4; ++r) {
      int row = wrow + mi * 16 + (lane >> 4) * 4 + r;
      float vv[8];
      float mx = -1e30f;
#pragma unroll
      for (int c = 0; c < 8; ++c) { vv[c] = sacc[mi][c][r] * scale; mx = fmaxf(mx, vv[c]); }
#pragma unroll
      for (int mm = 1; mm < 16; mm <<= 1) mx = fmaxf(mx, __shfl_xor(mx, mm, 64));
      float s_ = 0.f;
#pragma unroll
      for (int c = 0; c < 8; ++c) { vv[c] = __expf(vv[c] - mx); s_ += vv[c]; }
#pragma unroll
      for (int mm = 1; mm < 16; mm <<= 1) s_ += __shfl_xor(s_, mm, 64);
      sinv[mi][r] = 1.0f / s_;
#pragma unroll
      for (int c = 0; c < 8; ++c) {
        int col = c * 16 + (lane & 15);
        int byte = row * 256 + ((col * 2) ^ swz(row));
        *reinterpret_cast<unsigned short*>(reinterpret_cast<char*>(ps) + byte) = f2bf(vv[c]);
      }
    }

  // PV over four 32-wide s-chunks, double-buffered LDS (T3 2-phase).
  f32x4 oacc[2][16];
#pragma unroll
  for (int mi = 0; mi < 2; ++mi)
#pragma unroll
    for (int c = 0; c < 16; ++c) oacc[mi][c] = f32x4{0.f, 0.f, 0.f, 0.f};

#pragma unroll 1
  for (int cs = 0; cs < 4; ++cs) {
    __syncthreads();  // vs[cs&1] staged (vmcnt drained); cs-1 compute done
    if (cs < 3) {
      // STAGE next chunk into the other buffer; overlaps this chunk's MFMAs
#pragma unroll
      for (int it = 0; it < 4; ++it) {
        int ci = tid + it * 256;
        int d = ci >> 2, sc = ci & 3;
        gload16(vT + vBase + (long)d * 128 + (cs + 1) * 32 + (((sc * 16) ^ swz32(d)) >> 1),
                (char*)(&vs[(cs + 1) & 1][0]) + ci * 16);
      }
    }
    const int kglob = cs * 32 + kb_;
    bf8 ap[2];
#pragma unroll
    for (int mi = 0; mi < 2; ++mi) {
      int row = wrow + mi * 16 + (lane & 15);
      int byte = row * 256 + ((kglob * 2) ^ swz(row));
      ap[mi] = *reinterpret_cast<const bf8*>(reinterpret_cast<const char*>(ps) + byte);
    }
    __builtin_amdgcn_s_setprio(1);
#pragma unroll
    for (int c = 0; c < 16; ++c) {
      int d = c * 16 + (lane & 15);
      bf8 bv = *reinterpret_cast<const bf8*>(
          reinterpret_cast<const char*>(&vs[cs & 1][0]) + d * 64 + ((kb_ * 2) ^ swz32(d)));
#pragma unroll
      for (int mi = 0; mi < 2; ++mi)
        oacc[mi][c] = __builtin_amdgcn_mfma_f32_16x16x32_bf16(ap[mi], bv, oacc[mi][c], 0, 0, 0);
    }
    __builtin_amdgcn_s_setprio(0);
  }

  // write cat[b,t,h*256+d] = out/row_sum (bf16)
#pragma unroll
  for (int mi = 0; mi < 2; ++mi)
#pragma unroll
    for (int c = 0; c < 16; ++c)
#pragma unroll
      for (int r = 0; r < 4; ++r) {
        int tt = wrow + mi * 16 + (lane >> 4) * 4 + r;
        int d = c * 16 + (lane & 15);
        float v = oacc[mi][c][r] * sinv[mi][r];
        long off = ((long)b * 128 + tt) * 2048 + h * 256 + d;
        cat[off] = f2bf(v);
      }
}

// ---------------------------------------------------------------------------
// LayerNorm(a+b) with gamma/beta; optionally also write bf16 copy.
// ---------------------------------------------------------------------------
template<bool WB>
__global__ __launch_bounds__(256)
void ln_k(const float* __restrict__ a, const float* __restrict__ bsrc,
          const float* __restrict__ gamma, const float* __restrict__ beta,
          float* __restrict__ of, unsigned short* __restrict__ ob)
{
  const int row = blockIdx.x * 4 + (threadIdx.x >> 6);
  const int lane = threadIdx.x & 63;
  const long base = (long)row * 256 + lane * 4;
  f32x4 xa = *reinterpret_cast<const f32x4*>(a + base);
  f32x4 xb = *reinterpret_cast<const f32x4*>(bsrc + base);
  f32x4 x = xa + xb;
  float s = x[0] + x[1] + x[2] + x[3];
  float s2 = x[0] * x[0] + x[1] * x[1] + x[2] * x[2] + x[3] * x[3];
#pragma unroll
  for (int mm = 1; mm < 64; mm <<= 1) { s += __shfl_xor(s, mm, 64); s2 += __shfl_xor(s2, mm, 64); }
  float mean = s * (1.f / 256.f);
  float var = fmaxf(s2 * (1.f / 256.f) - mean * mean, 0.f);
  float inv = rsqrtf(var + 1e-5f);
  f32x4 g = *reinterpret_cast<const f32x4*>(gamma + lane * 4);
  f32x4 be = *reinterpret_cast<const f32x4*>(beta + lane * 4);
  f32x4 y;
#pragma unroll
  for (int j = 0; j < 4; ++j) y[j] = (x[j] - mean) * inv * g[j] + be[j];
  *reinterpret_cast<f32x4*>(of + base) = y;
  if constexpr (WB) {
    u16x4 w;
#pragma unroll
    for (int j = 0; j < 4; ++j) w[j] = f2bf(y[j]);
    *reinterpret_cast<u16x4*>(ob + base) = w;
  }
}

// ---------------------------------------------------------------------------
// hidden = silu(gate) * up, reading the fused gateup buffer:
// gate = gu[r*1024 + f], up = gu[r*1024 + 512 + f], out hid[r*512 + f].
// ---------------------------------------------------------------------------
__global__ __launch_bounds__(256)
void silu_k(const unsigned short* __restrict__ gu, unsigned short* __restrict__ o, long n)
{
  long i = ((long)blockIdx.x * 256 + threadIdx.x) * 8;
  if (i >= n) return;
  long r = i >> 9;
  int f = (int)(i & 511);
  const unsigned short* g = gu + r * 1024 + f;
  const unsigned short* u = g + 512;
  u16x4 g0 = *reinterpret_cast<const u16x4*>(g);
  u16x4 g1 = *reinterpret_cast<const u16x4*>(g + 4);
  u16x4 u0 = *reinterpret_cast<const u16x4*>(u);
  u16x4 u1 = *reinterpret_cast<const u16x4*>(u + 4);
  u16x4 o0, o1;
#pragma unroll
  for (int j = 0; j < 4; ++j) {
    float gg = bf2f(g0[j]), uu = bf2f(u0[j]);
    o0[j] = f2bf(gg / (1.f + __expf(-gg)) * uu);
    gg = bf2f(g1[j]); uu = bf2f(u1[j]);
    o1[j] = f2bf(gg / (1.f + __expf(-gg)) * uu);
  }
  *reinterpret_cast<u16x4*>(o + i) = o0;
  *reinterpret_cast<u16x4*>(o + i + 4) = o1;
}

// ---------------------------------------------------------------------------
// Workspace (304 MiB, lifetime reuse):
//   [0,16) Xb   [16,48) qkb (B*T*512 bf16 = 32MiB, q cols 0..255, k cols 256..511)
//   regA = ws+48MiB  (128MiB): vb(128) -> cat(128) -> gateup(64)|hid@64(32)
//   regB = ws+176MiB (128MiB): vT(128) -> attnp(32)|x1f@32(32)|x1b@64(16)|ffn@80(32)
// ---------------------------------------------------------------------------
extern "C" void kernel_launch(void* const* d_in, const int* in_sizes, int n_in,
                              void* d_out, int out_size, void* d_ws, size_t ws_size,
                              hipStream_t stream)
{
  const float* X  = (const float*)d_in[0];
  const float* Qw = (const float*)d_in[1];
  const float* Kw = (const float*)d_in[2];
  const float* Vw = (const float*)d_in[3];
  const float* Ow = (const float*)d_in[4];
  const float* Wg = (const float*)d_in[5];
  const float* Wu = (const float*)d_in[6];
  const float* Wd = (const float*)d_in[7];
  const float* g1 = (const float*)d_in[8];
  const float* b1 = (const float*)d_in[9];
  const float* g2 = (const float*)d_in[10];
  const float* b2 = (const float*)d_in[11];

  char* ws = (char*)d_ws;
  const size_t MiB = 1048576;
  unsigned short* Xb  = (unsigned short*)(ws);
  unsigned short* qkb = (unsigned short*)(ws + 16 * MiB);
  char* regA = ws + 48 * MiB;    // 128 MiB
  char* regB = regA + 128 * MiB; // 128 MiB

  unsigned short* vb     = (unsigned short*)regA;           // dead after trans_v
  unsigned short* vT     = (unsigned short*)regB;           // dead after attn_k
  unsigned short* cat    = (unsigned short*)regA;           // attn out (vb dead)
  float*          attnp  = (float*)(regB);                  // O-proj out (vT dead)
  float*          x1f    = (float*)(regB + 32 * MiB);
  unsigned short* x1b    = (unsigned short*)(regB + 64 * MiB);
  unsigned short* gateup = (unsigned short*)(regA);         // cat dead after O-proj
  unsigned short* hidb   = (unsigned short*)(regA + 64 * MiB);
  float*          ffn    = (float*)(regB + 80 * MiB);
  float* out = (float*)d_out;

  dim3 blk(256), gblk(512);
  cvt_bf<<<dim3(4096), blk, 0, stream>>>(X, Xb, (long)8388608);
  // Q|K fused: N=256 each, ldC=512, nx=4 (lognx=2) -> 512 blocks
  gemm_tk<true><<<dim3(512), gblk, 0, stream>>>(Xb, Qw, Kw, (void*)qkb, 256, 256, 2, 512);
  // V: nx=16 (lognx=4) -> 2048 blocks
  gemm_tk<true><<<dim3(2048), gblk, 0, stream>>>(Xb, Vw, Vw, (void*)vb, 256, 2048, 4, 2048);
  trans_v<<<dim3(32, 2048), blk, 0, stream>>>(vb, vT);
  attn_k<<<dim3(8, 256), blk, 0, stream>>>(qkb, vT, cat);
  // O-proj: nx=2 (lognx=1) -> 256 blocks
  gemm_tk<false><<<dim3(256), gblk, 0, stream>>>(cat, Ow, Ow, (void*)attnp, 2048, 256, 1, 256);
  ln_k<true><<<dim3(8192), blk, 0, stream>>>(X, attnp, g1, b1, x1f, x1b);
  // gate|up fused: N=512 each, ldC=1024, nx=8 (lognx=3) -> 1024 blocks
  gemm_tk<true><<<dim3(1024), gblk, 0, stream>>>(x1b, Wg, Wu, (void*)gateup, 256, 512, 3, 1024);
  silu_k<<<dim3(8192), blk, 0, stream>>>(gateup, hidb, (long)16777216);
  // down: nx=2 (lognx=1) -> 256 blocks
  gemm_tk<false><<<dim3(256), gblk, 0, stream>>>(hidb, Wd, Wd, (void*)ffn, 512, 256, 1, 256);
  ln_k<false><<<dim3(8192), blk, 0, stream>>>(x1f, ffn, g2, b2, out, (unsigned short*)nullptr);
}

// Round 9
// 565.873 us; speedup vs baseline: 1.2144x; 1.0377x over previous
//
#include <hip/hip_runtime.h>
#include <stdint.h>

// Problem constants: B=256, T=128, D=256, H=8, AE=32, DFF=512
#define DEVI static __device__ __forceinline__

typedef __attribute__((ext_vector_type(4))) float f32x4;
typedef __attribute__((ext_vector_type(8))) short bf8;     // 8 bf16 (MFMA A/B frag)
typedef __attribute__((ext_vector_type(4))) unsigned short u16x4;

DEVI unsigned short f2bf(float f) {
  unsigned u = __builtin_bit_cast(unsigned, f);
  u = (u + 0x7FFFu + ((u >> 16) & 1u)) >> 16;
  return (unsigned short)u;
}
DEVI float bf2f(unsigned short s) {
  return __builtin_bit_cast(float, ((unsigned)s) << 16);
}
DEVI unsigned cvt_pk_bf16(float lo, float hi) {
  unsigned r;
  asm("v_cvt_pk_bf16_f32 %0, %1, %2" : "=v"(r) : "v"(lo), "v"(hi));
  return r;
}
// swizzle for 256-B rows (attn ps): 16B granularity, 8 slots
DEVI int swz(int row) { return (((row >> 2) ^ row) & 7) << 4; }
// swizzle for 64-B rows (gemm As/Ws, attn vs): 16B granularity, 4 slots
DEVI int swz32(int row) { return (((row >> 1) ^ row) & 3) << 4; }

DEVI void gload16(const void* g, void* l) {
  __builtin_amdgcn_global_load_lds(
      (const __attribute__((address_space(1))) unsigned*)g,
      (__attribute__((address_space(3))) unsigned*)l, 16, 0, 0);
}

// ---------------------------------------------------------------------------
// Per-t batched GEMM: C[b,t, n0+*] = sum_k A[b,t,k] * Wsel[t,k,n]
// 2-phase pipeline (T3): dbuf As via global_load_lds (pre-swizzled source),
// dbuf Ws reg-staged fp32->bf16 cvt_pk, ONE barrier per K-tile, STAGE(next)
// before compute(cur). BM=256, BN=128, BK=32, 8 waves.
// 1-D grid, XCD same-t grouping + two-weight fusion. [= round-8 PASS]
// ---------------------------------------------------------------------------
template<bool OUT_BF16>
__global__ __launch_bounds__(512, 4)
void gemm_tk(const unsigned short* __restrict__ A, const float* __restrict__ W0,
             const float* __restrict__ W1, void* __restrict__ C,
             int Ka, int N, int lognx, int ldC)
{
  const int j = blockIdx.x;
  const int t = (j & 7) + ((j >> (3 + lognx)) << 3);
  const int nblk = (j >> 3) & ((1 << lognx) - 1);
  const int n0blk = nblk * 128;
  const float* Wsel = (n0blk >= N) ? W1 : W0;
  const int n0w = (n0blk >= N) ? (n0blk - N) : n0blk;

  const int tid = threadIdx.x;
  const int lane = tid & 63;
  const int wv = tid >> 6;        // 0..7
  const int wrow = wv * 32;

  __shared__ short As[2][256 * 32];  // [m][k] 64-B rows, swz32; 2 x 16KB
  __shared__ short Ws[2][128 * 32];  // [n][k] 64-B rows, swz32; 2 x 8KB

  f32x4 acc[2][8];
#pragma unroll
  for (int i = 0; i < 2; ++i)
#pragma unroll
    for (int jj = 0; jj < 8; ++jj) acc[i][jj] = f32x4{0.f, 0.f, 0.f, 0.f};

  const long ldA = 128L * Ka;
  const unsigned short* Ab = A + (long)t * Ka;
  const float* Wb = Wsel + (long)t * Ka * N + n0w;

  const int n0 = (tid & 31) * 4;  // 4 consecutive n per thread (W staging)
  const int kp = tid >> 5;        // k-pair 0..15 (W staging)

  // ---- prologue: stage tile 0 into As[0]/Ws[0]
#pragma unroll
  for (int it = 0; it < 2; ++it) {
    int ci = tid + it * 512;            // 16B chunk id; m=ci>>2
    int m = ci >> 2, cb = (ci & 3) * 16;
    gload16((const char*)(Ab + (long)m * ldA) + (cb ^ swz32(m)),
            (char*)(&As[0][0]) + ci * 16);
  }
  {
    f32x4 wlo = *(const f32x4*)(Wb + (long)(kp * 2) * N + n0);
    f32x4 whi = *(const f32x4*)(Wb + (long)(kp * 2 + 1) * N + n0);
#pragma unroll
    for (int jj = 0; jj < 4; ++jj) {
      int n = n0 + jj;
      *(unsigned*)((char*)(&Ws[0][0]) + n * 64 + ((kp * 4) ^ swz32(n))) =
          cvt_pk_bf16(wlo[jj], whi[jj]);
    }
  }

  const int nt = Ka >> 5;
  int cur = 0;
  for (int kt = 0; kt < nt; ++kt) {
    __syncthreads();  // drain: As[cur]/Ws[cur] ready, prior reads of other buf done
    const bool more = (kt + 1) < nt;
    f32x4 wlo, whi;
    if (more) {
      // STAGE(next) first: loads fly during compute, drained at next barrier
      const unsigned short* An = Ab + (kt + 1) * 32;
#pragma unroll
      for (int it = 0; it < 2; ++it) {
        int ci = tid + it * 512;
        int m = ci >> 2, cb = (ci & 3) * 16;
        gload16((const char*)(An + (long)m * ldA) + (cb ^ swz32(m)),
                (char*)(&As[cur ^ 1][0]) + ci * 16);
      }
      const float* Wn = Wb + (long)(kt + 1) * 32 * N;
      wlo = *(const f32x4*)(Wn + (long)(kp * 2) * N + n0);
      whi = *(const f32x4*)(Wn + (long)(kp * 2 + 1) * N + n0);
    }
    // ---- compute tile kt
    const int kb2 = (lane >> 4) * 16;  // k-chunk byte offset
    bf8 a0, a1;
    {
      const int m0 = wrow + (lane & 15);
      const int m1 = m0 + 16;
      a0 = *(const bf8*)((const char*)(&As[cur][0]) + m0 * 64 + (kb2 ^ swz32(m0)));
      a1 = *(const bf8*)((const char*)(&As[cur][0]) + m1 * 64 + (kb2 ^ swz32(m1)));
    }
#pragma unroll
    for (int ni = 0; ni < 8; ++ni) {
      const int n = ni * 16 + (lane & 15);
      bf8 bfr = *(const bf8*)((const char*)(&Ws[cur][0]) + n * 64 + (kb2 ^ swz32(n)));
      acc[0][ni] = __builtin_amdgcn_mfma_f32_16x16x32_bf16(a0, bfr, acc[0][ni], 0, 0, 0);
      acc[1][ni] = __builtin_amdgcn_mfma_f32_16x16x32_bf16(a1, bfr, acc[1][ni], 0, 0, 0);
    }
    if (more) {
#pragma unroll
      for (int jj = 0; jj < 4; ++jj) {
        int n = n0 + jj;
        *(unsigned*)((char*)(&Ws[cur ^ 1][0]) + n * 64 + ((kp * 4) ^ swz32(n))) =
            cvt_pk_bf16(wlo[jj], whi[jj]);
      }
    }
    cur ^= 1;
  }
  // epilogue: C/D layout col=lane&15, row=(lane>>4)*4+reg
#pragma unroll
  for (int mi = 0; mi < 2; ++mi)
#pragma unroll
    for (int ni = 0; ni < 8; ++ni)
#pragma unroll
      for (int r = 0; r < 4; ++r) {
        int m = wrow + mi * 16 + (lane >> 4) * 4 + r;
        int n = n0blk + ni * 16 + (lane & 15);
        long off = ((long)m * 128 + t) * ldC + n;
        float v = acc[mi][ni][r];
        if constexpr (OUT_BF16) reinterpret_cast<unsigned short*>(C)[off] = f2bf(v);
        else reinterpret_cast<float*>(C)[off] = v;
      }
}

// ---------------------------------------------------------------------------
// fp32 -> bf16 convert (X)
// ---------------------------------------------------------------------------
__global__ __launch_bounds__(256)
void cvt_bf(const float* __restrict__ in, unsigned short* __restrict__ out, long n)
{
  long i = ((long)blockIdx.x * 256 + threadIdx.x) * 8;
  if (i >= n) return;
  f32x4 a = *reinterpret_cast<const f32x4*>(in + i);
  f32x4 b = *reinterpret_cast<const f32x4*>(in + i + 4);
  u16x4 w0, w1;
#pragma unroll
  for (int j = 0; j < 4; ++j) { w0[j] = f2bf(a[j]); w1[j] = f2bf(b[j]); }
  *reinterpret_cast<u16x4*>(out + i) = w0;
  *reinterpret_cast<u16x4*>(out + i + 4) = w1;
}

// ---------------------------------------------------------------------------
// v (B,T,H*256) -> vT (B*H, 256, 128)   [known-good]
// ---------------------------------------------------------------------------
__global__ __launch_bounds__(256)
void trans_v(const unsigned short* __restrict__ vb, unsigned short* __restrict__ vT)
{
  const int bh = blockIdx.y;
  const int b = bh >> 3, h = bh & 7;
  const int tile = blockIdx.x;   // 0..31
  const int tt = tile >> 3;      // t-tile (4)
  const int td = tile & 7;       // d-tile (8)
  __shared__ unsigned short sm[32][33];
  const int rloc = threadIdx.x >> 3;
  const int q4 = (threadIdx.x & 7) * 4;
  {
    long off = ((long)b * 128 + tt * 32 + rloc) * 2048 + h * 256 + td * 32 + q4;
    u16x4 v = *reinterpret_cast<const u16x4*>(vb + off);
#pragma unroll
    for (int j = 0; j < 4; ++j) sm[rloc][q4 + j] = v[j];
  }
  __syncthreads();
  {
    u16x4 w;
#pragma unroll
    for (int j = 0; j < 4; ++j) w[j] = sm[q4 + j][rloc];
    long off = ((long)bh * 256 + td * 32 + rloc) * 128 + tt * 32 + q4;
    *reinterpret_cast<u16x4*>(vT + off) = w;
  }
}

// ---------------------------------------------------------------------------
// Fused attention for one (b,h).  [= round-8 PASS]
// ---------------------------------------------------------------------------
__global__ __launch_bounds__(256)
void attn_k(const unsigned short* __restrict__ qk, const unsigned short* __restrict__ vT,
            unsigned short* __restrict__ cat)
{
  const int h = blockIdx.x, b = blockIdx.y;
  const int tid = threadIdx.x, lane = tid & 63, wv = tid >> 6;
  const int wrow = wv * 32;

  __shared__ short ps[128 * 128];    // P [t][s] swizzled (256-B rows), 32KB
  __shared__ short vs[2][256 * 32];  // vT s-chunk [d][s32] 64-B rows swz32, 2x16KB

  const long qkBase = ((long)b * 128) * 512 + h * 32;
  const long vBase = ((long)(b * 8 + h)) * 256 * 128;
  const int kb_ = (lane >> 4) * 8;

  // stage s-chunk 0 into vs[0] (issue-only; drained at first barrier).
#pragma unroll
  for (int it = 0; it < 4; ++it) {
    int ci = tid + it * 256;
    int d = ci >> 2, sc = ci & 3;
    gload16(vT + vBase + (long)d * 128 + (((sc * 16) ^ swz32(d)) >> 1),
            (char*)(&vs[0][0]) + ci * 16);
  }

  // S = q k^T  (q/k frags straight from global; AE=32 = one MFMA K-step)
  f32x4 sacc[2][8];
#pragma unroll
  for (int mi = 0; mi < 2; ++mi)
#pragma unroll
    for (int c = 0; c < 8; ++c) sacc[mi][c] = f32x4{0.f, 0.f, 0.f, 0.f};
  bf8 aq[2];
#pragma unroll
  for (int mi = 0; mi < 2; ++mi) {
    int row = wrow + mi * 16 + (lane & 15);
    aq[mi] = *reinterpret_cast<const bf8*>(qk + qkBase + (long)row * 512 + kb_);
  }
#pragma unroll
  for (int ni = 0; ni < 8; ++ni) {
    int s = ni * 16 + (lane & 15);
    bf8 bk = *reinterpret_cast<const bf8*>(qk + qkBase + 256 + (long)s * 512 + kb_);
#pragma unroll
    for (int mi = 0; mi < 2; ++mi)
      sacc[mi][ni] = __builtin_amdgcn_mfma_f32_16x16x32_bf16(aq[mi], bk, sacc[mi][ni], 0, 0, 0);
  }

  // wave-parallel softmax; P written unnormalized (divide after PV)
  const float scale = 0.17677669529663687f;  // 1/sqrt(32)
  float sinv[2][4];
#pragma unroll
  for (int mi = 0; mi < 2; ++mi)
#pragma unroll
    for (int r = 0; r < 4; ++r) {
      int row = wrow + mi * 16 + (lane >> 4) * 4 + r;
      float vv[8];
      float mx = -1e30f;
#pragma unroll
      for (int c = 0; c < 8; ++c) { vv[c] = sacc[mi][c][r] * scale; mx = fmaxf(mx, vv[c]); }
#pragma unroll
      for (int mm = 1; mm < 16; mm <<= 1) mx = fmaxf(mx, __shfl_xor(mx, mm, 64));
      float s_ = 0.f;
#pragma unroll
      for (int c = 0; c < 8; ++c) { vv[c] = __expf(vv[c] - mx); s_ += vv[c]; }
#pragma unroll
      for (int mm = 1; mm < 16; mm <<= 1) s_ += __shfl_xor(s_, mm, 64);
      sinv[mi][r] = 1.0f / s_;
#pragma unroll
      for (int c = 0; c < 8; ++c) {
        int col = c * 16 + (lane & 15);
        int byte = row * 256 + ((col * 2) ^ swz(row));
        *reinterpret_cast<unsigned short*>(reinterpret_cast<char*>(ps) + byte) = f2bf(vv[c]);
      }
    }

  // PV over four 32-wide s-chunks, double-buffered LDS (T3 2-phase).
  f32x4 oacc[2][16];
#pragma unroll
  for (int mi = 0; mi < 2; ++mi)
#pragma unroll
    for (int c = 0; c < 16; ++c) oacc[mi][c] = f32x4{0.f, 0.f, 0.f, 0.f};

#pragma unroll 1
  for (int cs = 0; cs < 4; ++cs) {
    __syncthreads();  // vs[cs&1] staged (vmcnt drained); cs-1 compute done
    if (cs < 3) {
      // STAGE next chunk into the other buffer; overlaps this chunk's MFMAs
#pragma unroll
      for (int it = 0; it < 4; ++it) {
        int ci = tid + it * 256;
        int d = ci >> 2, sc = ci & 3;
        gload16(vT + vBase + (long)d * 128 + (cs + 1) * 32 + (((sc * 16) ^ swz32(d)) >> 1),
                (char*)(&vs[(cs + 1) & 1][0]) + ci * 16);
      }
    }
    const int kglob = cs * 32 + kb_;
    bf8 ap[2];
#pragma unroll
    for (int mi = 0; mi < 2; ++mi) {
      int row = wrow + mi * 16 + (lane & 15);
      int byte = row * 256 + ((kglob * 2) ^ swz(row));
      ap[mi] = *reinterpret_cast<const bf8*>(reinterpret_cast<const char*>(ps) + byte);
    }
    __builtin_amdgcn_s_setprio(1);
#pragma unroll
    for (int c = 0; c < 16; ++c) {
      int d = c * 16 + (lane & 15);
      bf8 bv = *reinterpret_cast<const bf8*>(
          reinterpret_cast<const char*>(&vs[cs & 1][0]) + d * 64 + ((kb_ * 2) ^ swz32(d)));
#pragma unroll
      for (int mi = 0; mi < 2; ++mi)
        oacc[mi][c] = __builtin_amdgcn_mfma_f32_16x16x32_bf16(ap[mi], bv, oacc[mi][c], 0, 0, 0);
    }
    __builtin_amdgcn_s_setprio(0);
  }

  // write cat[b,t,h*256+d] = out/row_sum (bf16)
#pragma unroll
  for (int mi = 0; mi < 2; ++mi)
#pragma unroll
    for (int c = 0; c < 16; ++c)
#pragma unroll
      for (int r = 0; r < 4; ++r) {
        int tt = wrow + mi * 16 + (lane >> 4) * 4 + r;
        int d = c * 16 + (lane & 15);
        float v = oacc[mi][c][r] * sinv[mi][r];
        long off = ((long)b * 128 + tt) * 2048 + h * 256 + d;
        cat[off] = f2bf(v);
      }
}

// ---------------------------------------------------------------------------
// LayerNorm(a+b): a,b read as bf16; write fp32 (WF) and/or bf16 (WB).
// Round 9: all residual-chain intermediates are bf16; x1f eliminated.
// ---------------------------------------------------------------------------
template<bool WF, bool WB>
__global__ __launch_bounds__(256)
void ln_k(const unsigned short* __restrict__ a, const unsigned short* __restrict__ bsrc,
          const float* __restrict__ gamma, const float* __restrict__ beta,
          float* __restrict__ of, unsigned short* __restrict__ ob)
{
  const int row = blockIdx.x * 4 + (threadIdx.x >> 6);
  const int lane = threadIdx.x & 63;
  const long base = (long)row * 256 + lane * 4;
  u16x4 ua = *reinterpret_cast<const u16x4*>(a + base);
  u16x4 ub = *reinterpret_cast<const u16x4*>(bsrc + base);
  f32x4 x;
#pragma unroll
  for (int j = 0; j < 4; ++j) x[j] = bf2f(ua[j]) + bf2f(ub[j]);
  float s = x[0] + x[1] + x[2] + x[3];
  float s2 = x[0] * x[0] + x[1] * x[1] + x[2] * x[2] + x[3] * x[3];
#pragma unroll
  for (int mm = 1; mm < 64; mm <<= 1) { s += __shfl_xor(s, mm, 64); s2 += __shfl_xor(s2, mm, 64); }
  float mean = s * (1.f / 256.f);
  float var = fmaxf(s2 * (1.f / 256.f) - mean * mean, 0.f);
  float inv = rsqrtf(var + 1e-5f);
  f32x4 g = *reinterpret_cast<const f32x4*>(gamma + lane * 4);
  f32x4 be = *reinterpret_cast<const f32x4*>(beta + lane * 4);
  f32x4 y;
#pragma unroll
  for (int j = 0; j < 4; ++j) y[j] = (x[j] - mean) * inv * g[j] + be[j];
  if constexpr (WF) *reinterpret_cast<f32x4*>(of + base) = y;
  if constexpr (WB) {
    u16x4 w;
#pragma unroll
    for (int j = 0; j < 4; ++j) w[j] = f2bf(y[j]);
    *reinterpret_cast<u16x4*>(ob + base) = w;
  }
}

// ---------------------------------------------------------------------------
// hidden = silu(gate) * up, reading the fused gateup buffer.
// ---------------------------------------------------------------------------
__global__ __launch_bounds__(256)
void silu_k(const unsigned short* __restrict__ gu, unsigned short* __restrict__ o, long n)
{
  long i = ((long)blockIdx.x * 256 + threadIdx.x) * 8;
  if (i >= n) return;
  long r = i >> 9;
  int f = (int)(i & 511);
  const unsigned short* g = gu + r * 1024 + f;
  const unsigned short* u = g + 512;
  u16x4 g0 = *reinterpret_cast<const u16x4*>(g);
  u16x4 g1 = *reinterpret_cast<const u16x4*>(g + 4);
  u16x4 u0 = *reinterpret_cast<const u16x4*>(u);
  u16x4 u1 = *reinterpret_cast<const u16x4*>(u + 4);
  u16x4 o0, o1;
#pragma unroll
  for (int j = 0; j < 4; ++j) {
    float gg = bf2f(g0[j]), uu = bf2f(u0[j]);
    o0[j] = f2bf(gg / (1.f + __expf(-gg)) * uu);
    gg = bf2f(g1[j]); uu = bf2f(u1[j]);
    o1[j] = f2bf(gg / (1.f + __expf(-gg)) * uu);
  }
  *reinterpret_cast<u16x4*>(o + i) = o0;
  *reinterpret_cast<u16x4*>(o + i + 4) = o1;
}

// ---------------------------------------------------------------------------
// Workspace (304 MiB, lifetime reuse). All LN-chain intermediates bf16:
//   [0,16) Xb   [16,48) qkb
//   regA @48MiB (128): vb(128) -> cat(128) -> gateup(64)|hid@64(32)
//   regB @176MiB (128): vT(128) -> attnpb@0(16)|x1b@16(16)|ffnb@32(16)
// ---------------------------------------------------------------------------
extern "C" void kernel_launch(void* const* d_in, const int* in_sizes, int n_in,
                              void* d_out, int out_size, void* d_ws, size_t ws_size,
                              hipStream_t stream)
{
  const float* X  = (const float*)d_in[0];
  const float* Qw = (const float*)d_in[1];
  const float* Kw = (const float*)d_in[2];
  const float* Vw = (const float*)d_in[3];
  const float* Ow = (const float*)d_in[4];
  const float* Wg = (const float*)d_in[5];
  const float* Wu = (const float*)d_in[6];
  const float* Wd = (const float*)d_in[7];
  const float* g1 = (const float*)d_in[8];
  const float* b1 = (const float*)d_in[9];
  const float* g2 = (const float*)d_in[10];
  const float* b2 = (const float*)d_in[11];

  char* ws = (char*)d_ws;
  const size_t MiB = 1048576;
  unsigned short* Xb  = (unsigned short*)(ws);
  unsigned short* qkb = (unsigned short*)(ws + 16 * MiB);
  char* regA = ws + 48 * MiB;    // 128 MiB
  char* regB = regA + 128 * MiB; // 128 MiB

  unsigned short* vb     = (unsigned short*)regA;           // dead after trans_v
  unsigned short* vT     = (unsigned short*)regB;           // dead after attn_k
  unsigned short* cat    = (unsigned short*)regA;           // attn out (vb dead)
  unsigned short* attnpb = (unsigned short*)(regB);         // O-proj out bf16 (vT dead)
  unsigned short* x1b    = (unsigned short*)(regB + 16 * MiB);
  unsigned short* ffnb   = (unsigned short*)(regB + 32 * MiB);
  unsigned short* gateup = (unsigned short*)(regA);         // cat dead after O-proj
  unsigned short* hidb   = (unsigned short*)(regA + 64 * MiB);
  float* out = (float*)d_out;

  dim3 blk(256), gblk(512);
  cvt_bf<<<dim3(4096), blk, 0, stream>>>(X, Xb, (long)8388608);
  // Q|K fused: N=256 each, ldC=512, nx=4 (lognx=2) -> 512 blocks
  gemm_tk<true><<<dim3(512), gblk, 0, stream>>>(Xb, Qw, Kw, (void*)qkb, 256, 256, 2, 512);
  // V: nx=16 (lognx=4) -> 2048 blocks
  gemm_tk<true><<<dim3(2048), gblk, 0, stream>>>(Xb, Vw, Vw, (void*)vb, 256, 2048, 4, 2048);
  trans_v<<<dim3(32, 2048), blk, 0, stream>>>(vb, vT);
  attn_k<<<dim3(8, 256), blk, 0, stream>>>(qkb, vT, cat);
  // O-proj -> bf16: nx=2 (lognx=1) -> 256 blocks
  gemm_tk<true><<<dim3(256), gblk, 0, stream>>>(cat, Ow, Ow, (void*)attnpb, 2048, 256, 1, 256);
  // ln1: x1 = LN(Xb + attnpb) -> x1b only (x1f eliminated)
  ln_k<false, true><<<dim3(8192), blk, 0, stream>>>(Xb, attnpb, g1, b1, (float*)nullptr, x1b);
  // gate|up fused: N=512 each, ldC=1024, nx=8 (lognx=3) -> 1024 blocks
  gemm_tk<true><<<dim3(1024), gblk, 0, stream>>>(x1b, Wg, Wu, (void*)gateup, 256, 512, 3, 1024);
  silu_k<<<dim3(8192), blk, 0, stream>>>(gateup, hidb, (long)16777216);
  // down -> bf16: nx=2 (lognx=1) -> 256 blocks
  gemm_tk<true><<<dim3(256), gblk, 0, stream>>>(hidb, Wd, Wd, (void*)ffnb, 512, 256, 1, 256);
  // ln2: out = LN(x1b + ffnb) -> fp32 d_out
  ln_k<true, false><<<dim3(8192), blk, 0, stream>>>(x1b, ffnb, g2, b2, out, (unsigned short*)nullptr);
}

// Round 10
// 541.365 us; speedup vs baseline: 1.2694x; 1.0453x over previous
//
#include <hip/hip_runtime.h>
#include <stdint.h>

// Problem constants: B=256, T=128, D=256, H=8, AE=32, DFF=512
#define DEVI static __device__ __forceinline__

typedef __attribute__((ext_vector_type(4))) float f32x4;
typedef __attribute__((ext_vector_type(8))) short bf8;     // 8 bf16 (MFMA A/B frag)
typedef __attribute__((ext_vector_type(4))) unsigned short u16x4;

DEVI unsigned short f2bf(float f) {
  unsigned u = __builtin_bit_cast(unsigned, f);
  u = (u + 0x7FFFu + ((u >> 16) & 1u)) >> 16;
  return (unsigned short)u;
}
DEVI float bf2f(unsigned short s) {
  return __builtin_bit_cast(float, ((unsigned)s) << 16);
}
DEVI unsigned cvt_pk_bf16(float lo, float hi) {
  unsigned r;
  asm("v_cvt_pk_bf16_f32 %0, %1, %2" : "=v"(r) : "v"(lo), "v"(hi));
  return r;
}
// swizzle for 256-B rows (attn ps): 16B granularity, 8 slots
DEVI int swz(int row) { return (((row >> 2) ^ row) & 7) << 4; }
// swizzle for 64-B rows (gemm As/Ws, attn vs): 16B granularity, 4 slots
DEVI int swz32(int row) { return (((row >> 1) ^ row) & 3) << 4; }

DEVI void gload16(const void* g, void* l) {
  __builtin_amdgcn_global_load_lds(
      (const __attribute__((address_space(1))) unsigned*)g,
      (__attribute__((address_space(3))) unsigned*)l, 16, 0, 0);
}

// ---------------------------------------------------------------------------
// Per-t batched GEMM: C[b,t, n0+*] = sum_k A[b,t,k] * Wsel[t,k,n]
// 2-phase pipeline (T3): dbuf As via global_load_lds (pre-swizzled source),
// dbuf Ws reg-staged fp32->bf16 cvt_pk, ONE barrier per K-tile, STAGE(next)
// before compute(cur). BM=256, BN=128, BK=32, 8 waves.
// 1-D grid, XCD same-t grouping + two-weight fusion. [= round-8/9 PASS]
// ---------------------------------------------------------------------------
template<bool OUT_BF16>
__global__ __launch_bounds__(512, 4)
void gemm_tk(const unsigned short* __restrict__ A, const float* __restrict__ W0,
             const float* __restrict__ W1, void* __restrict__ C,
             int Ka, int N, int lognx, int ldC)
{
  const int j = blockIdx.x;
  const int t = (j & 7) + ((j >> (3 + lognx)) << 3);
  const int nblk = (j >> 3) & ((1 << lognx) - 1);
  const int n0blk = nblk * 128;
  const float* Wsel = (n0blk >= N) ? W1 : W0;
  const int n0w = (n0blk >= N) ? (n0blk - N) : n0blk;

  const int tid = threadIdx.x;
  const int lane = tid & 63;
  const int wv = tid >> 6;        // 0..7
  const int wrow = wv * 32;

  __shared__ short As[2][256 * 32];  // [m][k] 64-B rows, swz32; 2 x 16KB
  __shared__ short Ws[2][128 * 32];  // [n][k] 64-B rows, swz32; 2 x 8KB

  f32x4 acc[2][8];
#pragma unroll
  for (int i = 0; i < 2; ++i)
#pragma unroll
    for (int jj = 0; jj < 8; ++jj) acc[i][jj] = f32x4{0.f, 0.f, 0.f, 0.f};

  const long ldA = 128L * Ka;
  const unsigned short* Ab = A + (long)t * Ka;
  const float* Wb = Wsel + (long)t * Ka * N + n0w;

  const int n0 = (tid & 31) * 4;  // 4 consecutive n per thread (W staging)
  const int kp = tid >> 5;        // k-pair 0..15 (W staging)

  // ---- prologue: stage tile 0 into As[0]/Ws[0]
#pragma unroll
  for (int it = 0; it < 2; ++it) {
    int ci = tid + it * 512;            // 16B chunk id; m=ci>>2
    int m = ci >> 2, cb = (ci & 3) * 16;
    gload16((const char*)(Ab + (long)m * ldA) + (cb ^ swz32(m)),
            (char*)(&As[0][0]) + ci * 16);
  }
  {
    f32x4 wlo = *(const f32x4*)(Wb + (long)(kp * 2) * N + n0);
    f32x4 whi = *(const f32x4*)(Wb + (long)(kp * 2 + 1) * N + n0);
#pragma unroll
    for (int jj = 0; jj < 4; ++jj) {
      int n = n0 + jj;
      *(unsigned*)((char*)(&Ws[0][0]) + n * 64 + ((kp * 4) ^ swz32(n))) =
          cvt_pk_bf16(wlo[jj], whi[jj]);
    }
  }

  const int nt = Ka >> 5;
  int cur = 0;
  for (int kt = 0; kt < nt; ++kt) {
    __syncthreads();  // drain: As[cur]/Ws[cur] ready, prior reads of other buf done
    const bool more = (kt + 1) < nt;
    f32x4 wlo, whi;
    if (more) {
      // STAGE(next) first: loads fly during compute, drained at next barrier
      const unsigned short* An = Ab + (kt + 1) * 32;
#pragma unroll
      for (int it = 0; it < 2; ++it) {
        int ci = tid + it * 512;
        int m = ci >> 2, cb = (ci & 3) * 16;
        gload16((const char*)(An + (long)m * ldA) + (cb ^ swz32(m)),
                (char*)(&As[cur ^ 1][0]) + ci * 16);
      }
      const float* Wn = Wb + (long)(kt + 1) * 32 * N;
      wlo = *(const f32x4*)(Wn + (long)(kp * 2) * N + n0);
      whi = *(const f32x4*)(Wn + (long)(kp * 2 + 1) * N + n0);
    }
    // ---- compute tile kt
    const int kb2 = (lane >> 4) * 16;  // k-chunk byte offset
    bf8 a0, a1;
    {
      const int m0 = wrow + (lane & 15);
      const int m1 = m0 + 16;
      a0 = *(const bf8*)((const char*)(&As[cur][0]) + m0 * 64 + (kb2 ^ swz32(m0)));
      a1 = *(const bf8*)((const char*)(&As[cur][0]) + m1 * 64 + (kb2 ^ swz32(m1)));
    }
#pragma unroll
    for (int ni = 0; ni < 8; ++ni) {
      const int n = ni * 16 + (lane & 15);
      bf8 bfr = *(const bf8*)((const char*)(&Ws[cur][0]) + n * 64 + (kb2 ^ swz32(n)));
      acc[0][ni] = __builtin_amdgcn_mfma_f32_16x16x32_bf16(a0, bfr, acc[0][ni], 0, 0, 0);
      acc[1][ni] = __builtin_amdgcn_mfma_f32_16x16x32_bf16(a1, bfr, acc[1][ni], 0, 0, 0);
    }
    if (more) {
#pragma unroll
      for (int jj = 0; jj < 4; ++jj) {
        int n = n0 + jj;
        *(unsigned*)((char*)(&Ws[cur ^ 1][0]) + n * 64 + ((kp * 4) ^ swz32(n))) =
            cvt_pk_bf16(wlo[jj], whi[jj]);
      }
    }
    cur ^= 1;
  }
  // epilogue: C/D layout col=lane&15, row=(lane>>4)*4+reg
#pragma unroll
  for (int mi = 0; mi < 2; ++mi)
#pragma unroll
    for (int ni = 0; ni < 8; ++ni)
#pragma unroll
      for (int r = 0; r < 4; ++r) {
        int m = wrow + mi * 16 + (lane >> 4) * 4 + r;
        int n = n0blk + ni * 16 + (lane & 15);
        long off = ((long)m * 128 + t) * ldC + n;
        float v = acc[mi][ni][r];
        if constexpr (OUT_BF16) reinterpret_cast<unsigned short*>(C)[off] = f2bf(v);
        else reinterpret_cast<float*>(C)[off] = v;
      }
}

// ---------------------------------------------------------------------------
// fp32 -> bf16 convert (X)
// ---------------------------------------------------------------------------
__global__ __launch_bounds__(256)
void cvt_bf(const float* __restrict__ in, unsigned short* __restrict__ out, long n)
{
  long i = ((long)blockIdx.x * 256 + threadIdx.x) * 8;
  if (i >= n) return;
  f32x4 a = *reinterpret_cast<const f32x4*>(in + i);
  f32x4 b = *reinterpret_cast<const f32x4*>(in + i + 4);
  u16x4 w0, w1;
#pragma unroll
  for (int j = 0; j < 4; ++j) { w0[j] = f2bf(a[j]); w1[j] = f2bf(b[j]); }
  *reinterpret_cast<u16x4*>(out + i) = w0;
  *reinterpret_cast<u16x4*>(out + i + 4) = w1;
}

// ---------------------------------------------------------------------------
// v (B,T,H*256) -> vT (B*H, 256, 128)   [known-good]
// ---------------------------------------------------------------------------
__global__ __launch_bounds__(256)
void trans_v(const unsigned short* __restrict__ vb, unsigned short* __restrict__ vT)
{
  const int bh = blockIdx.y;
  const int b = bh >> 3, h = bh & 7;
  const int tile = blockIdx.x;   // 0..31
  const int tt = tile >> 3;      // t-tile (4)
  const int td = tile & 7;       // d-tile (8)
  __shared__ unsigned short sm[32][33];
  const int rloc = threadIdx.x >> 3;
  const int q4 = (threadIdx.x & 7) * 4;
  {
    long off = ((long)b * 128 + tt * 32 + rloc) * 2048 + h * 256 + td * 32 + q4;
    u16x4 v = *reinterpret_cast<const u16x4*>(vb + off);
#pragma unroll
    for (int j = 0; j < 4; ++j) sm[rloc][q4 + j] = v[j];
  }
  __syncthreads();
  {
    u16x4 w;
#pragma unroll
    for (int j = 0; j < 4; ++j) w[j] = sm[q4 + j][rloc];
    long off = ((long)bh * 256 + td * 32 + rloc) * 128 + tt * 32 + q4;
    *reinterpret_cast<u16x4*>(vT + off) = w;
  }
}

// ---------------------------------------------------------------------------
// Fused attention for one (b,h). Round 10: 512 threads / 8 waves, 16 t-rows
// per wave (was 256 thr / 4 waves / 32 rows). Per-output-row math and k-order
// IDENTICAL to round 9 (bitwise same output); only the wave->row mapping and
// staging indexing changed. LDS unchanged (ps 32KB + vs 2x16KB).
// ---------------------------------------------------------------------------
__global__ __launch_bounds__(512, 4)
void attn_k(const unsigned short* __restrict__ qk, const unsigned short* __restrict__ vT,
            unsigned short* __restrict__ cat)
{
  const int h = blockIdx.x, b = blockIdx.y;
  const int tid = threadIdx.x, lane = tid & 63, wv = tid >> 6;
  const int wrow = wv * 16;          // 16 rows per wave

  __shared__ short ps[128 * 128];    // P [t][s] swizzled (256-B rows), 32KB
  __shared__ short vs[2][256 * 32];  // vT s-chunk [d][s32] 64-B rows swz32, 2x16KB

  const long qkBase = ((long)b * 128) * 512 + h * 32;
  const long vBase = ((long)(b * 8 + h)) * 256 * 128;
  const int kb_ = (lane >> 4) * 8;

  // stage s-chunk 0 into vs[0] (issue-only; drained at first barrier).
#pragma unroll
  for (int it = 0; it < 2; ++it) {
    int ci = tid + it * 512;
    int d = ci >> 2, sc = ci & 3;
    gload16(vT + vBase + (long)d * 128 + (((sc * 16) ^ swz32(d)) >> 1),
            (char*)(&vs[0][0]) + ci * 16);
  }

  // S = q k^T  (q/k frags straight from global; AE=32 = one MFMA K-step)
  f32x4 sacc[8];
#pragma unroll
  for (int c = 0; c < 8; ++c) sacc[c] = f32x4{0.f, 0.f, 0.f, 0.f};
  bf8 aq;
  {
    int row = wrow + (lane & 15);
    aq = *reinterpret_cast<const bf8*>(qk + qkBase + (long)row * 512 + kb_);
  }
#pragma unroll
  for (int ni = 0; ni < 8; ++ni) {
    int s = ni * 16 + (lane & 15);
    bf8 bk = *reinterpret_cast<const bf8*>(qk + qkBase + 256 + (long)s * 512 + kb_);
    sacc[ni] = __builtin_amdgcn_mfma_f32_16x16x32_bf16(aq, bk, sacc[ni], 0, 0, 0);
  }

  // wave-parallel softmax; P written unnormalized (divide after PV)
  const float scale = 0.17677669529663687f;  // 1/sqrt(32)
  float sinv[4];
#pragma unroll
  for (int r = 0; r < 4; ++r) {
    int row = wrow + (lane >> 4) * 4 + r;
    float vv[8];
    float mx = -1e30f;
#pragma unroll
    for (int c = 0; c < 8; ++c) { vv[c] = sacc[c][r] * scale; mx = fmaxf(mx, vv[c]); }
#pragma unroll
    for (int mm = 1; mm < 16; mm <<= 1) mx = fmaxf(mx, __shfl_xor(mx, mm, 64));
    float s_ = 0.f;
#pragma unroll
    for (int c = 0; c < 8; ++c) { vv[c] = __expf(vv[c] - mx); s_ += vv[c]; }
#pragma unroll
    for (int mm = 1; mm < 16; mm <<= 1) s_ += __shfl_xor(s_, mm, 64);
    sinv[r] = 1.0f / s_;
#pragma unroll
    for (int c = 0; c < 8; ++c) {
      int col = c * 16 + (lane & 15);
      int byte = row * 256 + ((col * 2) ^ swz(row));
      *reinterpret_cast<unsigned short*>(reinterpret_cast<char*>(ps) + byte) = f2bf(vv[c]);
    }
  }

  // PV over four 32-wide s-chunks, double-buffered LDS (T3 2-phase).
  f32x4 oacc[16];
#pragma unroll
  for (int c = 0; c < 16; ++c) oacc[c] = f32x4{0.f, 0.f, 0.f, 0.f};

#pragma unroll 1
  for (int cs = 0; cs < 4; ++cs) {
    __syncthreads();  // vs[cs&1] staged (vmcnt drained); cs-1 compute done
    if (cs < 3) {
      // STAGE next chunk into the other buffer; overlaps this chunk's MFMAs
#pragma unroll
      for (int it = 0; it < 2; ++it) {
        int ci = tid + it * 512;
        int d = ci >> 2, sc = ci & 3;
        gload16(vT + vBase + (long)d * 128 + (cs + 1) * 32 + (((sc * 16) ^ swz32(d)) >> 1),
                (char*)(&vs[(cs + 1) & 1][0]) + ci * 16);
      }
    }
    const int kglob = cs * 32 + kb_;
    bf8 ap;
    {
      int row = wrow + (lane & 15);
      int byte = row * 256 + ((kglob * 2) ^ swz(row));
      ap = *reinterpret_cast<const bf8*>(reinterpret_cast<const char*>(ps) + byte);
    }
    __builtin_amdgcn_s_setprio(1);
#pragma unroll
    for (int c = 0; c < 16; ++c) {
      int d = c * 16 + (lane & 15);
      bf8 bv = *reinterpret_cast<const bf8*>(
          reinterpret_cast<const char*>(&vs[cs & 1][0]) + d * 64 + ((kb_ * 2) ^ swz32(d)));
      oacc[c] = __builtin_amdgcn_mfma_f32_16x16x32_bf16(ap, bv, oacc[c], 0, 0, 0);
    }
    __builtin_amdgcn_s_setprio(0);
  }

  // write cat[b,t,h*256+d] = out/row_sum (bf16)
#pragma unroll
  for (int c = 0; c < 16; ++c)
#pragma unroll
    for (int r = 0; r < 4; ++r) {
      int tt = wrow + (lane >> 4) * 4 + r;
      int d = c * 16 + (lane & 15);
      float v = oacc[c][r] * sinv[r];
      long off = ((long)b * 128 + tt) * 2048 + h * 256 + d;
      cat[off] = f2bf(v);
    }
}

// ---------------------------------------------------------------------------
// LayerNorm(a+b): a,b read as bf16; write fp32 (WF) and/or bf16 (WB).
// ---------------------------------------------------------------------------
template<bool WF, bool WB>
__global__ __launch_bounds__(256)
void ln_k(const unsigned short* __restrict__ a, const unsigned short* __restrict__ bsrc,
          const float* __restrict__ gamma, const float* __restrict__ beta,
          float* __restrict__ of, unsigned short* __restrict__ ob)
{
  const int row = blockIdx.x * 4 + (threadIdx.x >> 6);
  const int lane = threadIdx.x & 63;
  const long base = (long)row * 256 + lane * 4;
  u16x4 ua = *reinterpret_cast<const u16x4*>(a + base);
  u16x4 ub = *reinterpret_cast<const u16x4*>(bsrc + base);
  f32x4 x;
#pragma unroll
  for (int j = 0; j < 4; ++j) x[j] = bf2f(ua[j]) + bf2f(ub[j]);
  float s = x[0] + x[1] + x[2] + x[3];
  float s2 = x[0] * x[0] + x[1] * x[1] + x[2] * x[2] + x[3] * x[3];
#pragma unroll
  for (int mm = 1; mm < 64; mm <<= 1) { s += __shfl_xor(s, mm, 64); s2 += __shfl_xor(s2, mm, 64); }
  float mean = s * (1.f / 256.f);
  float var = fmaxf(s2 * (1.f / 256.f) - mean * mean, 0.f);
  float inv = rsqrtf(var + 1e-5f);
  f32x4 g = *reinterpret_cast<const f32x4*>(gamma + lane * 4);
  f32x4 be = *reinterpret_cast<const f32x4*>(beta + lane * 4);
  f32x4 y;
#pragma unroll
  for (int j = 0; j < 4; ++j) y[j] = (x[j] - mean) * inv * g[j] + be[j];
  if constexpr (WF) *reinterpret_cast<f32x4*>(of + base) = y;
  if constexpr (WB) {
    u16x4 w;
#pragma unroll
    for (int j = 0; j < 4; ++j) w[j] = f2bf(y[j]);
    *reinterpret_cast<u16x4*>(ob + base) = w;
  }
}

// ---------------------------------------------------------------------------
// hidden = silu(gate) * up, reading the fused gateup buffer.
// ---------------------------------------------------------------------------
__global__ __launch_bounds__(256)
void silu_k(const unsigned short* __restrict__ gu, unsigned short* __restrict__ o, long n)
{
  long i = ((long)blockIdx.x * 256 + threadIdx.x) * 8;
  if (i >= n) return;
  long r = i >> 9;
  int f = (int)(i & 511);
  const unsigned short* g = gu + r * 1024 + f;
  const unsigned short* u = g + 512;
  u16x4 g0 = *reinterpret_cast<const u16x4*>(g);
  u16x4 g1 = *reinterpret_cast<const u16x4*>(g + 4);
  u16x4 u0 = *reinterpret_cast<const u16x4*>(u);
  u16x4 u1 = *reinterpret_cast<const u16x4*>(u + 4);
  u16x4 o0, o1;
#pragma unroll
  for (int j = 0; j < 4; ++j) {
    float gg = bf2f(g0[j]), uu = bf2f(u0[j]);
    o0[j] = f2bf(gg / (1.f + __expf(-gg)) * uu);
    gg = bf2f(g1[j]); uu = bf2f(u1[j]);
    o1[j] = f2bf(gg / (1.f + __expf(-gg)) * uu);
  }
  *reinterpret_cast<u16x4*>(o + i) = o0;
  *reinterpret_cast<u16x4*>(o + i + 4) = o1;
}

// ---------------------------------------------------------------------------
// Workspace (304 MiB, lifetime reuse). All LN-chain intermediates bf16:
//   [0,16) Xb   [16,48) qkb
//   regA @48MiB (128): vb(128) -> cat(128) -> gateup(64)|hid@64(32)
//   regB @176MiB (128): vT(128) -> attnpb@0(16)|x1b@16(16)|ffnb@32(16)
// ---------------------------------------------------------------------------
extern "C" void kernel_launch(void* const* d_in, const int* in_sizes, int n_in,
                              void* d_out, int out_size, void* d_ws, size_t ws_size,
                              hipStream_t stream)
{
  const float* X  = (const float*)d_in[0];
  const float* Qw = (const float*)d_in[1];
  const float* Kw = (const float*)d_in[2];
  const float* Vw = (const float*)d_in[3];
  const float* Ow = (const float*)d_in[4];
  const float* Wg = (const float*)d_in[5];
  const float* Wu = (const float*)d_in[6];
  const float* Wd = (const float*)d_in[7];
  const float* g1 = (const float*)d_in[8];
  const float* b1 = (const float*)d_in[9];
  const float* g2 = (const float*)d_in[10];
  const float* b2 = (const float*)d_in[11];

  char* ws = (char*)d_ws;
  const size_t MiB = 1048576;
  unsigned short* Xb  = (unsigned short*)(ws);
  unsigned short* qkb = (unsigned short*)(ws + 16 * MiB);
  char* regA = ws + 48 * MiB;    // 128 MiB
  char* regB = regA + 128 * MiB; // 128 MiB

  unsigned short* vb     = (unsigned short*)regA;           // dead after trans_v
  unsigned short* vT     = (unsigned short*)regB;           // dead after attn_k
  unsigned short* cat    = (unsigned short*)regA;           // attn out (vb dead)
  unsigned short* attnpb = (unsigned short*)(regB);         // O-proj out bf16 (vT dead)
  unsigned short* x1b    = (unsigned short*)(regB + 16 * MiB);
  unsigned short* ffnb   = (unsigned short*)(regB + 32 * MiB);
  unsigned short* gateup = (unsigned short*)(regA);         // cat dead after O-proj
  unsigned short* hidb   = (unsigned short*)(regA + 64 * MiB);
  float* out = (float*)d_out;

  dim3 blk(256), gblk(512);
  cvt_bf<<<dim3(4096), blk, 0, stream>>>(X, Xb, (long)8388608);
  // Q|K fused: N=256 each, ldC=512, nx=4 (lognx=2) -> 512 blocks
  gemm_tk<true><<<dim3(512), gblk, 0, stream>>>(Xb, Qw, Kw, (void*)qkb, 256, 256, 2, 512);
  // V: nx=16 (lognx=4) -> 2048 blocks
  gemm_tk<true><<<dim3(2048), gblk, 0, stream>>>(Xb, Vw, Vw, (void*)vb, 256, 2048, 4, 2048);
  trans_v<<<dim3(32, 2048), blk, 0, stream>>>(vb, vT);
  attn_k<<<dim3(8, 256), gblk, 0, stream>>>(qkb, vT, cat);
  // O-proj -> bf16: nx=2 (lognx=1) -> 256 blocks
  gemm_tk<true><<<dim3(256), gblk, 0, stream>>>(cat, Ow, Ow, (void*)attnpb, 2048, 256, 1, 256);
  // ln1: x1 = LN(Xb + attnpb) -> x1b only
  ln_k<false, true><<<dim3(8192), blk, 0, stream>>>(Xb, attnpb, g1, b1, (float*)nullptr, x1b);
  // gate|up fused: N=512 each, ldC=1024, nx=8 (lognx=3) -> 1024 blocks
  gemm_tk<true><<<dim3(1024), gblk, 0, stream>>>(x1b, Wg, Wu, (void*)gateup, 256, 512, 3, 1024);
  silu_k<<<dim3(8192), blk, 0, stream>>>(gateup, hidb, (long)16777216);
  // down -> bf16: nx=2 (lognx=1) -> 256 blocks
  gemm_tk<true><<<dim3(256), gblk, 0, stream>>>(hidb, Wd, Wd, (void*)ffnb, 512, 256, 1, 256);
  // ln2: out = LN(x1b + ffnb) -> fp32 d_out
  ln_k<true, false><<<dim3(8192), blk, 0, stream>>>(x1b, ffnb, g2, b2, out, (unsigned short*)nullptr);
}